// Round 5
// baseline (709.156 us; speedup 1.0000x reference)
//
#include <hip/hip_runtime.h>
#include <hip/hip_bf16.h>
#include <math.h>

typedef __attribute__((ext_vector_type(8))) short bf16x8;     // 8 bf16 = 4 VGPRs
typedef __attribute__((ext_vector_type(4))) float f32x4;      // MFMA accumulator
typedef __attribute__((ext_vector_type(8))) unsigned short u16x8;

typedef const float* fptr;
typedef const unsigned short* bfp;

__device__ inline float b2f(unsigned short u) {
    union { unsigned int i; float f; } v; v.i = ((unsigned int)u) << 16; return v.f;
}
__device__ inline unsigned short f2b(float x) {
    __hip_bfloat16 h = __float2bfloat16(x);
    return *(unsigned short*)&h;
}
#define BF2F(x) __bfloat162float(x)
__device__ inline float elu_f(float x) { return x > 0.f ? x : expm1f(x); }

// async global->LDS, 16 bytes per lane; lds dest = wave-uniform base + lane*16
__device__ inline void load_lds16(const void* g, void* l) {
    __builtin_amdgcn_global_load_lds(
        (const __attribute__((address_space(1))) unsigned int*)g,
        (__attribute__((address_space(3))) unsigned int*)l, 16, 0, 0);
}

// ---------------------------------------------------------------------------
// Kernel 0: transpose+convert W (fp32 [k][n]) -> Wt (bf16 [n][k]); z==2 builds
// Wbt (bf16 [mid][d] = Wb^T). grid (16,16,3), block 256.
// ---------------------------------------------------------------------------
__global__ __launch_bounds__(256) void convert_w(
    fptr W0, fptr W1, fptr Wb, unsigned short* Wt0, unsigned short* Wt1,
    unsigned short* Wbt)
{
    __shared__ float tl[64][65];
    __shared__ unsigned short tb[8192];
    int t = threadIdx.x;
    if (blockIdx.z == 2) {
        if (blockIdx.x || blockIdx.y) return;
        for (int i = 0; i < 32; i++) {
            int idx = i * 256 + t;             // idx = d*64 + mid
            tb[(idx & 63) * 128 + (idx >> 6)] = f2b(Wb[idx]);
        }
        __syncthreads();
        for (int i = 0; i < 4; i++) {
            int o = (i * 256 + t) * 8;
            *(u16x8*)&Wbt[o] = *(const u16x8*)&tb[o];
        }
        return;
    }
    fptr W = blockIdx.z ? W1 : W0;
    unsigned short* Wt = blockIdx.z ? Wt1 : Wt0;
    int k0 = blockIdx.x * 64, n0 = blockIdx.y * 64;
    #pragma unroll
    for (int i = 0; i < 16; i++) {
        int kl = i * 4 + (t >> 6), nl = t & 63;
        tl[kl][nl] = W[(size_t)(k0 + kl) * 1024 + n0 + nl];
    }
    __syncthreads();
    #pragma unroll
    for (int i = 0; i < 16; i++) {
        int nl = i * 4 + (t >> 6), kl = t & 63;
        Wt[(size_t)(n0 + nl) * 1024 + k0 + kl] = f2b(tl[kl][nl]);
    }
}

// ---------------------------------------------------------------------------
// Kernel 0b: convert A fp32 -> bf16 contiguous. grid (16384), block 256.
// ---------------------------------------------------------------------------
__global__ __launch_bounds__(256) void convert_a(fptr A, unsigned short* B)
{
    size_t idx = ((size_t)blockIdx.x * 256 + threadIdx.x) * 8;
    const float4* ap = (const float4*)(A + idx);
    float4 a0 = ap[0], a1 = ap[1];
    u16x8 p = { f2b(a0.x), f2b(a0.y), f2b(a0.z), f2b(a0.w),
                f2b(a1.x), f2b(a1.y), f2b(a1.z), f2b(a1.w) };
    *(u16x8*)(B + idx) = p;
}

// ---------------------------------------------------------------------------
// Kernel 1: small in_proj (query->q, value1->v1), fp32 in/out (ws)
// ---------------------------------------------------------------------------
__global__ __launch_bounds__(256) void small_proj(
    fptr x0, fptr W0, fptr b0, fptr g0, fptr be0,
    fptr x1, fptr W1, fptr b1, fptr g1, fptr be1,
    float* out0, float* out1)
{
    __shared__ float xs[1024];
    __shared__ float part[2][128];
    __shared__ float r4[4][2];
    int hgrp = blockIdx.x;
    int row  = blockIdx.y;
    int which = blockIdx.z;
    fptr x  = which ? x1  : x0;
    fptr W  = which ? W1  : W0;
    fptr bi = which ? b1  : b0;
    fptr g  = which ? g1  : g0;
    fptr be = which ? be1 : be0;
    float* outp = which ? out1 : out0;
    int t = threadIdx.x, lane = t & 63, wv = t >> 6;
    for (int i = t; i < 1024; i += 256) xs[i] = x[row * 1024 + i];
    __syncthreads();
    int cl = t & 127, kh = t >> 7;
    int col = hgrp * 128 + cl;
    float acc = 0.f;
    const float* wp = W + (size_t)(kh * 512) * 1024 + col;
    for (int k = 0; k < 512; k++) acc += xs[kh * 512 + k] * wp[(size_t)k * 1024];
    part[kh][cl] = acc;
    __syncthreads();
    float e = 0.f;
    if (t < 128) e = elu_f(part[0][t] + part[1][t] + bi[col]);
    float s = e, ss = e * e;
    for (int m = 32; m > 0; m >>= 1) { s += __shfl_xor(s, m); ss += __shfl_xor(ss, m); }
    if (lane == 0) { r4[wv][0] = s; r4[wv][1] = ss; }
    __syncthreads();
    float S  = r4[0][0] + r4[1][0] + r4[2][0] + r4[3][0];
    float SS = r4[0][1] + r4[1][1] + r4[2][1] + r4[3][1];
    float mean = S * (1.f / 128.f);
    float var  = SS * (1.f / 128.f) - mean * mean;
    float inv  = rsqrtf(var + 1e-3f);
    if (t < 128) outp[row * 1024 + col] = (e - mean) * inv * g[col] + be[col];
}

// ---------------------------------------------------------------------------
// Kernel 1b: qwb[bh][mid][d] = Wbt[mid][d] * q[b,h,d]  (bf16). grid(128).
// ---------------------------------------------------------------------------
__global__ __launch_bounds__(256) void qwb_prep(
    bfp Wbt, const float* qws, unsigned short* qwbuf)
{
    int bh = blockIdx.x;
    int b = bh >> 3, h = bh & 7;
    int t = threadIdx.x;
    #pragma unroll
    for (int i = 0; i < 4; i++) {
        int idx = (i * 256 + t) * 8;       // elem index (8-aligned; 128%8==0)
        int d = idx & 127;
        u16x8 wv = *(const u16x8*)&Wbt[idx];
        const float* qp = qws + b * 1024 + h * 128 + d;
        u16x8 o;
        #pragma unroll
        for (int j = 0; j < 8; j++) o[j] = f2b(b2f(wv[j]) * qp[j]);
        *(u16x8*)&qwbuf[(size_t)bh * 8192 + idx] = o;
    }
}

// ---------------------------------------------------------------------------
// Kernel 2 (fast path): m97-style bf16 GEMM, BK=64 as two 32-panels.
// grid(256, 8): blockIdx.x = ROW tile (XCD swizzle: the 8 n-sharers of a
// row tile get wg_id === rt (mod 8) -> same XCD -> A fetched ~once).
// Epilogue: bias + elu + groupnorm fused (verified R2-R4). Z bf16.
// ---------------------------------------------------------------------------
__global__ __launch_bounds__(256) void mfma_gemm_bf(
    bfp A, bfp Wt, fptr bias, fptr g, fptr be, __hip_bfloat16* Z)
{
    __shared__ unsigned short As[2][128][32];
    __shared__ unsigned short Bs[2][128][32];
    __shared__ float sstat[128][2][2];
    int r0 = blockIdx.x * 128;     // row tile
    int n0 = blockIdx.y * 128;     // col tile
    int t = threadIdx.x, lane = t & 63, w = t >> 6;
    int c = lane & 15, q = lane >> 4;
    int rowbase = (w & 1) * 64, colbase = (w >> 1) * 64;

    f32x4 acc[4][4];
    const f32x4 fzero = {0.f, 0.f, 0.f, 0.f};
    #pragma unroll
    for (int i = 0; i < 4; i++)
        #pragma unroll
        for (int j = 0; j < 4; j++) acc[i][j] = fzero;

    int srow = lane >> 2;            // 0..15 within a 16-row issue
    int sseg = (lane & 3) * 8;       // k offset (8 bf16 = 16 B)
    const unsigned short* ag = A  + (size_t)(r0 + w * 32 + srow) * 1024 + sseg;
    const unsigned short* bg = Wt + (size_t)(n0 + w * 32 + srow) * 1024 + sseg;

    for (int k0 = 0; k0 < 1024; k0 += 64) {
        load_lds16(ag + k0,                  &As[0][w * 32][0]);
        load_lds16(ag + k0 + 16 * 1024,      &As[0][w * 32 + 16][0]);
        load_lds16(ag + k0 + 32,             &As[1][w * 32][0]);
        load_lds16(ag + k0 + 32 + 16 * 1024, &As[1][w * 32 + 16][0]);
        load_lds16(bg + k0,                  &Bs[0][w * 32][0]);
        load_lds16(bg + k0 + 16 * 1024,      &Bs[0][w * 32 + 16][0]);
        load_lds16(bg + k0 + 32,             &Bs[1][w * 32][0]);
        load_lds16(bg + k0 + 32 + 16 * 1024, &Bs[1][w * 32 + 16][0]);
        __syncthreads();
        #pragma unroll
        for (int p = 0; p < 2; p++) {
            bf16x8 af[4], bfv[4];
            #pragma unroll
            for (int i = 0; i < 4; i++) af[i]  = *(const bf16x8*)&As[p][rowbase + i * 16 + c][q * 8];
            #pragma unroll
            for (int j = 0; j < 4; j++) bfv[j] = *(const bf16x8*)&Bs[p][colbase + j * 16 + c][q * 8];
            #pragma unroll
            for (int i = 0; i < 4; i++)
                #pragma unroll
                for (int j = 0; j < 4; j++)
                    acc[i][j] = __builtin_amdgcn_mfma_f32_16x16x32_bf16(af[i], bfv[j], acc[i][j], 0, 0, 0);
        }
        __syncthreads();
    }

    float bcol[4], gcol[4], Bcol[4];
    #pragma unroll
    for (int j = 0; j < 4; j++) {
        int cg = n0 + colbase + j * 16 + c;
        bcol[j] = bias[cg]; gcol[j] = g[cg]; Bcol[j] = be[cg];
    }
    #pragma unroll
    for (int i = 0; i < 4; i++)
        #pragma unroll
        for (int j = 0; j < 4; j++)
            #pragma unroll
            for (int r = 0; r < 4; r++)
                acc[i][j][r] = elu_f(acc[i][j][r] + bcol[j]);
    #pragma unroll
    for (int i = 0; i < 4; i++) {
        #pragma unroll
        for (int r = 0; r < 4; r++) {
            float s  = acc[i][0][r] + acc[i][1][r] + acc[i][2][r] + acc[i][3][r];
            float ss = acc[i][0][r] * acc[i][0][r] + acc[i][1][r] * acc[i][1][r]
                     + acc[i][2][r] * acc[i][2][r] + acc[i][3][r] * acc[i][3][r];
            for (int m = 1; m < 16; m <<= 1) { s += __shfl_xor(s, m); ss += __shfl_xor(ss, m); }
            if (c == 0) {
                int rl = rowbase + i * 16 + q * 4 + r;
                sstat[rl][w >> 1][0] = s;
                sstat[rl][w >> 1][1] = ss;
            }
        }
    }
    __syncthreads();
    #pragma unroll
    for (int i = 0; i < 4; i++) {
        #pragma unroll
        for (int r = 0; r < 4; r++) {
            int rl = rowbase + i * 16 + q * 4 + r;
            float S  = sstat[rl][0][0] + sstat[rl][1][0];
            float SS = sstat[rl][0][1] + sstat[rl][1][1];
            float mean = S * (1.f / 128.f);
            float var  = SS * (1.f / 128.f) - mean * mean;
            float inv  = rsqrtf(var + 1e-3f);
            #pragma unroll
            for (int j = 0; j < 4; j++) {
                int cg = n0 + colbase + j * 16 + c;
                float v = (acc[i][j][r] - mean) * inv * gcol[j] + Bcol[j];
                Z[(size_t)(r0 + rl) * 1024 + cg] = __float2bfloat16(v);
            }
        }
    }
}

// ---------------------------------------------------------------------------
// Kernel 2 (fallback, R3-proven): fp32 A staged with in-kernel cvt.
// ---------------------------------------------------------------------------
__global__ __launch_bounds__(256) void mfma_gemm_f32(
    fptr A0, bfp Wt0, fptr b0, fptr g0, fptr be0,
    fptr A1, bfp Wt1, fptr b1, fptr g1, fptr be1,
    __hip_bfloat16* Z0, __hip_bfloat16* Z1)
{
    __shared__ unsigned short As[128][32];
    __shared__ unsigned short Bs[128][32];
    __shared__ float sstat[128][2][2];
    int zi = blockIdx.z;
    fptr A    = zi ? A1 : A0;
    bfp Wt    = zi ? Wt1 : Wt0;
    fptr bias = zi ? b1 : b0;
    fptr g    = zi ? g1 : g0;
    fptr be   = zi ? be1 : be0;
    __hip_bfloat16* Z = zi ? Z1 : Z0;
    int n0 = blockIdx.x * 128;
    int r0 = blockIdx.y * 128;
    int t = threadIdx.x, lane = t & 63, w = t >> 6;
    int c = lane & 15, q = lane >> 4;
    int rowbase = (w & 1) * 64, colbase = (w >> 1) * 64;

    f32x4 acc[4][4];
    const f32x4 fzero = {0.f, 0.f, 0.f, 0.f};
    #pragma unroll
    for (int i = 0; i < 4; i++)
        #pragma unroll
        for (int j = 0; j < 4; j++) acc[i][j] = fzero;

    int arow = t >> 1, aseg = (t & 1) * 16;
    int srow = lane >> 2, sseg = (lane & 3) * 8;
    const unsigned short* bg = Wt + (size_t)(n0 + w * 32 + srow) * 1024 + sseg;

    for (int k0 = 0; k0 < 1024; k0 += 32) {
        load_lds16(bg + k0,             &Bs[w * 32][0]);
        load_lds16(bg + k0 + 16 * 1024, &Bs[w * 32 + 16][0]);
        const float4* ap = (const float4*)(A + (size_t)(r0 + arow) * 1024 + k0 + aseg);
        float4 a0 = ap[0], a1 = ap[1], a2 = ap[2], a3 = ap[3];
        u16x8 p0 = { f2b(a0.x), f2b(a0.y), f2b(a0.z), f2b(a0.w),
                     f2b(a1.x), f2b(a1.y), f2b(a1.z), f2b(a1.w) };
        u16x8 p1 = { f2b(a2.x), f2b(a2.y), f2b(a2.z), f2b(a2.w),
                     f2b(a3.x), f2b(a3.y), f2b(a3.z), f2b(a3.w) };
        *(u16x8*)&As[arow][aseg]     = p0;
        *(u16x8*)&As[arow][aseg + 8] = p1;
        __syncthreads();
        bf16x8 af[4], bfv[4];
        #pragma unroll
        for (int i = 0; i < 4; i++) af[i]  = *(const bf16x8*)&As[rowbase + i * 16 + c][q * 8];
        #pragma unroll
        for (int j = 0; j < 4; j++) bfv[j] = *(const bf16x8*)&Bs[colbase + j * 16 + c][q * 8];
        #pragma unroll
        for (int i = 0; i < 4; i++)
            #pragma unroll
            for (int j = 0; j < 4; j++)
                acc[i][j] = __builtin_amdgcn_mfma_f32_16x16x32_bf16(af[i], bfv[j], acc[i][j], 0, 0, 0);
        __syncthreads();
    }

    float bcol[4], gcol[4], Bcol[4];
    #pragma unroll
    for (int j = 0; j < 4; j++) {
        int cg = n0 + colbase + j * 16 + c;
        bcol[j] = bias[cg]; gcol[j] = g[cg]; Bcol[j] = be[cg];
    }
    #pragma unroll
    for (int i = 0; i < 4; i++)
        #pragma unroll
        for (int j = 0; j < 4; j++)
            #pragma unroll
            for (int r = 0; r < 4; r++)
                acc[i][j][r] = elu_f(acc[i][j][r] + bcol[j]);
    #pragma unroll
    for (int i = 0; i < 4; i++) {
        #pragma unroll
        for (int r = 0; r < 4; r++) {
            float s  = acc[i][0][r] + acc[i][1][r] + acc[i][2][r] + acc[i][3][r];
            float ss = acc[i][0][r] * acc[i][0][r] + acc[i][1][r] * acc[i][1][r]
                     + acc[i][2][r] * acc[i][2][r] + acc[i][3][r] * acc[i][3][r];
            for (int m = 1; m < 16; m <<= 1) { s += __shfl_xor(s, m); ss += __shfl_xor(ss, m); }
            if (c == 0) {
                int rl = rowbase + i * 16 + q * 4 + r;
                sstat[rl][w >> 1][0] = s;
                sstat[rl][w >> 1][1] = ss;
            }
        }
    }
    __syncthreads();
    #pragma unroll
    for (int i = 0; i < 4; i++) {
        #pragma unroll
        for (int r = 0; r < 4; r++) {
            int rl = rowbase + i * 16 + q * 4 + r;
            float S  = sstat[rl][0][0] + sstat[rl][1][0];
            float SS = sstat[rl][0][1] + sstat[rl][1][1];
            float mean = S * (1.f / 128.f);
            float var  = SS * (1.f / 128.f) - mean * mean;
            float inv  = rsqrtf(var + 1e-3f);
            #pragma unroll
            for (int j = 0; j < 4; j++) {
                int cg = n0 + colbase + j * 16 + c;
                float v = (acc[i][j][r] - mean) * inv * gcol[j] + Bcol[j];
                Z[(size_t)(r0 + rl) * 1024 + cg] = __float2bfloat16(v);
            }
        }
    }
}

// ---------------------------------------------------------------------------
// Kernel 3: attn_basic = k @ (q .* Wb) via pure MFMA GEMM.
// A = zK rows (bf16) staged via global_load_lds; B = qwb[bh] (bf16 [mid][d]).
// 4 K-panels of 32 staged at once; 1 barrier; 32 MFMA/wave.
// grid (mt=16, b=16, h=8), block 256 (wave w -> m rows w*32..+31).
// ---------------------------------------------------------------------------
__global__ __launch_bounds__(256) void attn_basic(
    const __hip_bfloat16* kbuf, bfp qwb, fptr maskp,
    fptr bbp, fptr Wl1, fptr bl1,
    float* logits, float* poolpart)
{
    __shared__ unsigned short As[4][128][32];  // 32 KB
    __shared__ unsigned short Bs[4][64][32];   // 16 KB
    __shared__ float masksh[128];
    __shared__ float poolred[4][64];
    int mt = blockIdx.x, b = blockIdx.y, h = blockIdx.z;
    int t = threadIdx.x, lane = t & 63, w = t >> 6;
    int c = lane & 15, q = lane >> 4;

    if (t < 128) masksh[t] = maskp[b * 2048 + mt * 128 + t];

    int srow = lane >> 2, sseg = (lane & 3) * 8;
    const unsigned short* ag = (const unsigned short*)kbuf
        + (size_t)(b * 2048 + mt * 128 + w * 32 + srow) * 1024 + h * 128 + sseg;
    const unsigned short* bg = qwb + (size_t)(b * 8 + h) * 8192
        + (w * 16 + srow) * 128 + sseg;

    #pragma unroll
    for (int p = 0; p < 4; p++) {
        load_lds16(ag + p * 32,             &As[p][w * 32][0]);
        load_lds16(ag + p * 32 + 16 * 1024, &As[p][w * 32 + 16][0]);
        load_lds16(bg + p * 32,             &Bs[p][w * 16][0]);
    }
    __syncthreads();

    f32x4 acc[2][4];
    const f32x4 fzero = {0.f, 0.f, 0.f, 0.f};
    #pragma unroll
    for (int i = 0; i < 2; i++)
        #pragma unroll
        for (int j = 0; j < 4; j++) acc[i][j] = fzero;
    #pragma unroll
    for (int p = 0; p < 4; p++) {
        bf16x8 af[2], bfv[4];
        #pragma unroll
        for (int i = 0; i < 2; i++) af[i]  = *(const bf16x8*)&As[p][w * 32 + i * 16 + c][q * 8];
        #pragma unroll
        for (int j = 0; j < 4; j++) bfv[j] = *(const bf16x8*)&Bs[p][j * 16 + c][q * 8];
        #pragma unroll
        for (int i = 0; i < 2; i++)
            #pragma unroll
            for (int j = 0; j < 4; j++)
                acc[i][j] = __builtin_amdgcn_mfma_f32_16x16x32_bf16(af[i], bfv[j], acc[i][j], 0, 0, 0);
    }

    float bbs[4], wl1s[4];
    #pragma unroll
    for (int j = 0; j < 4; j++) { bbs[j] = bbp[j * 16 + c]; wl1s[j] = Wl1[j * 16 + c]; }
    float bl1v = bl1[0];
    float pp[4] = {0.f, 0.f, 0.f, 0.f};
    #pragma unroll
    for (int i = 0; i < 2; i++) {
        #pragma unroll
        for (int r = 0; r < 4; r++) {
            int ml = w * 32 + i * 16 + q * 4 + r;
            float mv = masksh[ml];
            float lg = 0.f;
            #pragma unroll
            for (int j = 0; j < 4; j++) {
                float basic = fmaxf(acc[i][j][r] + bbs[j], 0.f);
                lg += basic * wl1s[j];
                pp[j] += basic * mv;
            }
            lg += __shfl_xor(lg, 1); lg += __shfl_xor(lg, 2);
            lg += __shfl_xor(lg, 4); lg += __shfl_xor(lg, 8);
            if (c == 0)
                logits[((size_t)(b * 8 + h)) * 2048 + mt * 128 + ml] = lg + bl1v;
        }
    }
    #pragma unroll
    for (int j = 0; j < 4; j++) {
        pp[j] += __shfl_xor(pp[j], 16);
        pp[j] += __shfl_xor(pp[j], 32);
    }
    if (lane < 16) {
        #pragma unroll
        for (int j = 0; j < 4; j++) poolred[w][j * 16 + c] = pp[j];
    }
    __syncthreads();
    if (t < 64) {
        float p = poolred[0][t] + poolred[1][t] + poolred[2][t] + poolred[3][t];
        poolpart[((size_t)((b * 8 + h) * 16 + mt)) * 64 + t] = p;
    }
}

// ---------------------------------------------------------------------------
// Kernel 4a: softmax -> normalized alph (in-place over logits), pool, ach
// ---------------------------------------------------------------------------
__global__ __launch_bounds__(256) void softmax_pool(
    const float* logits, const float* poolpart, fptr maskp,
    fptr Wl2, fptr bl2, float* alphws, float* achws)
{
    __shared__ float alph[2048];
    __shared__ float red[4];
    __shared__ float redm[4];
    __shared__ float pools[64];
    int h = blockIdx.x, b = blockIdx.y;
    int t = threadIdx.x, lane = t & 63, wv = t >> 6;

    const float* lg = logits + (size_t)(b * 8 + h) * 2048;
    float msum_l = 0.f, mx_l = -1e30f;
    for (int i = t; i < 2048; i += 256) {
        float mv = maskp[b * 2048 + i];
        msum_l += mv;
        float v = (mv == 0.f) ? -1e9f : lg[i];
        alph[i] = v;
        mx_l = fmaxf(mx_l, v);
    }
    for (int mm = 32; mm > 0; mm >>= 1) {
        msum_l += __shfl_xor(msum_l, mm);
        mx_l = fmaxf(mx_l, __shfl_xor(mx_l, mm));
    }
    if (lane == 0) { red[wv] = msum_l; redm[wv] = mx_l; }
    __syncthreads();
    float msum = red[0] + red[1] + red[2] + red[3];
    float mx = fmaxf(fmaxf(redm[0], redm[1]), fmaxf(redm[2], redm[3]));

    float se = 0.f;
    for (int i = t; i < 2048; i += 256) {
        float e = expf(alph[i] - mx);
        alph[i] = e;
        se += e;
    }
    for (int mm = 32; mm > 0; mm >>= 1) se += __shfl_xor(se, mm);
    __syncthreads();
    if (lane == 0) red[wv] = se;
    __syncthreads();
    float invS = 1.f / (red[0] + red[1] + red[2] + red[3]);
    for (int i = t; i < 2048; i += 256)
        alphws[(size_t)(b * 8 + h) * 2048 + i] = alph[i] * invS;

    if (t < 64) {
        const float* pq = poolpart + ((size_t)(b * 8 + h) * 16) * 64 + t;
        float p = 0.f;
        for (int pt = 0; pt < 16; pt++) p += pq[pt * 64];
        pools[t] = p / msum;
    }
    __syncthreads();
    if (t < 128) {
        float s2 = bl2[t];
        for (int mid = 0; mid < 64; mid++) s2 += pools[mid] * Wl2[mid * 128 + t];
        achws[(b * 8 + h) * 128 + t] = 1.f / (1.f + expf(-s2));
    }
}

// ---------------------------------------------------------------------------
// Kernel 4b: v2 aggregation partials. grid (seg=4, h=8, b=16), block 256.
// ---------------------------------------------------------------------------
__global__ __launch_bounds__(256) void v2agg(
    const float* alphws, const __hip_bfloat16* v2buf, float* v2part)
{
    __shared__ float redl[4][128];
    int seg = blockIdx.x, h = blockIdx.y, b = blockIdx.z;
    int t = threadIdx.x, lane = t & 63, wv = t >> 6;
    int mo = lane >> 4, d8 = (lane & 15) * 8;
    const float* al = alphws + (size_t)(b * 8 + h) * 2048;
    float acc[8] = {};
    for (int it = 0; it < 32; it++) {
        int m = seg * 512 + it * 16 + wv * 4 + mo;
        bf16x8 v8 = *(const bf16x8*)&v2buf[((size_t)(b * 2048 + m)) * 1024 + h * 128 + d8];
        float a = al[m];
        #pragma unroll
        for (int j = 0; j < 8; j++)
            acc[j] += a * b2f(((unsigned short*)&v8)[j]);
    }
    #pragma unroll
    for (int j = 0; j < 8; j++) {
        acc[j] += __shfl_xor(acc[j], 16);
        acc[j] += __shfl_xor(acc[j], 32);
    }
    if (lane < 16) {
        #pragma unroll
        for (int j = 0; j < 8; j++) redl[wv][d8 + j] = acc[j];
    }
    __syncthreads();
    if (t < 128) {
        float s = redl[0][t] + redl[1][t] + redl[2][t] + redl[3][t];
        v2part[((size_t)((b * 8 + h) * 4 + seg)) * 128 + t] = s;
    }
}

// ---------------------------------------------------------------------------
// Kernel 4c: combine partials, out = v1 * agg * ach (fp32). grid (16).
// ---------------------------------------------------------------------------
__global__ __launch_bounds__(256) void out_combine(
    const float* v2part, const float* achws, const float* v1ws, float* out)
{
    int b = blockIdx.x, t = threadIdx.x;
    for (int e = t; e < 1024; e += 256) {
        int h = e >> 7, d = e & 127;
        const float* vp = v2part + ((size_t)((b * 8 + h) * 4)) * 128 + d;
        float s = vp[0] + vp[128] + vp[256] + vp[384];
        out[b * 1024 + e] = v1ws[b * 1024 + e] * s * achws[(b * 8 + h) * 128 + d];
    }
}

// ---------------------------------------------------------------------------
extern "C" void kernel_launch(void* const* d_in, const int* in_sizes, int n_in,
                              void* d_out, int out_size, void* d_ws, size_t ws_size,
                              hipStream_t stream) {
    fptr query  = (fptr)d_in[0];
    fptr key    = (fptr)d_in[1];
    fptr maskp  = (fptr)d_in[2];
    fptr value1 = (fptr)d_in[3];
    fptr value2 = (fptr)d_in[4];
    fptr Wq = (fptr)d_in[5],  bq = (fptr)d_in[6],  gq = (fptr)d_in[7],  Bq = (fptr)d_in[8];
    fptr Wk = (fptr)d_in[9],  bk = (fptr)d_in[10], gk = (fptr)d_in[11], Bk = (fptr)d_in[12];
    fptr Wv1 = (fptr)d_in[13], bv1 = (fptr)d_in[14], gv1 = (fptr)d_in[15], Bv1 = (fptr)d_in[16];
    fptr Wv2 = (fptr)d_in[17], bv2 = (fptr)d_in[18], gv2 = (fptr)d_in[19], Bv2 = (fptr)d_in[20];
    fptr Wb = (fptr)d_in[21], bb = (fptr)d_in[22];
    fptr Wl1 = (fptr)d_in[23], bl1 = (fptr)d_in[24];
    fptr Wl2 = (fptr)d_in[25], bl2 = (fptr)d_in[26];

    const size_t MB = 1024 * 1024;
    char* w = (char*)d_ws;
    __hip_bfloat16* zK  = (__hip_bfloat16*)w;                        // 64 MB
    __hip_bfloat16* zV2 = (__hip_bfloat16*)(w + 64 * MB);            // 64 MB
    unsigned short* WtK  = (unsigned short*)(w + 128 * MB);          // 2 MB
    unsigned short* WtV2 = (unsigned short*)(w + 130 * MB);          // 2 MB
    unsigned short* Wbt  = (unsigned short*)(w + 132 * MB);          // 16 KB
    unsigned short* qwbuf = (unsigned short*)(w + 132 * MB + 65536); // 2 MB
    float* qws      = (float*)(w + 132 * MB + 65536 + 2 * MB);       // 64 KB
    float* v1ws     = qws + 16 * 1024;                               // 64 KB
    float* logits   = v1ws + 16 * 1024;                              // 1 MB
    float* poolpart = logits + 16 * 8 * 2048;                        // 512 KB
    float* achws    = poolpart + 16 * 8 * 16 * 64;                   // 64 KB
    float* v2part   = achws + 16 * 8 * 128;                          // 256 KB -> ends at 136 MB
    float* alphws   = logits;                                        // in-place softmax
    unsigned short* Abf = (unsigned short*)(w + 136 * MB);           // 64 MB (fast path)
    float* out = (float*)d_out;

    bool fast = ws_size >= 200 * MB;

    hipLaunchKernelGGL(convert_w, dim3(16, 16, 3), dim3(256), 0, stream,
                       Wk, Wv2, Wb, WtK, WtV2, Wbt);
    hipLaunchKernelGGL(small_proj, dim3(8, 16, 2), dim3(256), 0, stream,
                       query, Wq, bq, gq, Bq, value1, Wv1, bv1, gv1, Bv1, qws, v1ws);
    hipLaunchKernelGGL(qwb_prep, dim3(128), dim3(256), 0, stream,
                       (bfp)Wbt, qws, qwbuf);
    if (fast) {
        hipLaunchKernelGGL(convert_a, dim3(16384), dim3(256), 0, stream, key, Abf);
        hipLaunchKernelGGL(mfma_gemm_bf, dim3(256, 8), dim3(256), 0, stream,
                           (bfp)Abf, (bfp)WtK, bk, gk, Bk, zK);
        hipLaunchKernelGGL(convert_a, dim3(16384), dim3(256), 0, stream, value2, Abf);
        hipLaunchKernelGGL(mfma_gemm_bf, dim3(256, 8), dim3(256), 0, stream,
                           (bfp)Abf, (bfp)WtV2, bv2, gv2, Bv2, zV2);
    } else {
        hipLaunchKernelGGL(mfma_gemm_f32, dim3(8, 256, 2), dim3(256), 0, stream,
                           key, (bfp)WtK, bk, gk, Bk, value2, (bfp)WtV2, bv2, gv2, Bv2, zK, zV2);
    }
    hipLaunchKernelGGL(attn_basic, dim3(16, 16, 8), dim3(256), 0, stream,
                       zK, (bfp)qwbuf, maskp, bb, Wl1, bl1, logits, poolpart);
    hipLaunchKernelGGL(softmax_pool, dim3(8, 16), dim3(256), 0, stream,
                       logits, poolpart, maskp, Wl2, bl2, alphws, achws);
    hipLaunchKernelGGL(v2agg, dim3(4, 8, 16), dim3(256), 0, stream,
                       alphws, zV2, v2part);
    hipLaunchKernelGGL(out_combine, dim3(16), dim3(256), 0, stream,
                       v2part, achws, v1ws, out);
}

// Round 6
// 686.355 us; speedup vs baseline: 1.0332x; 1.0332x over previous
//
#include <hip/hip_runtime.h>
#include <hip/hip_bf16.h>
#include <math.h>

typedef __attribute__((ext_vector_type(8))) short bf16x8;     // 8 bf16 = 4 VGPRs
typedef __attribute__((ext_vector_type(4))) float f32x4;      // MFMA accumulator
typedef __attribute__((ext_vector_type(8))) unsigned short u16x8;

typedef const float* fptr;
typedef const unsigned short* bfp;

__device__ inline float b2f(unsigned short u) {
    union { unsigned int i; float f; } v; v.i = ((unsigned int)u) << 16; return v.f;
}
__device__ inline unsigned short f2b(float x) {
    __hip_bfloat16 h = __float2bfloat16(x);
    return *(unsigned short*)&h;
}
__device__ inline float elu_f(float x) { return x > 0.f ? x : expm1f(x); }

// async global->LDS, 16 bytes per lane; lds dest = wave-uniform base + lane*16
__device__ inline void load_lds16(const void* g, void* l) {
    __builtin_amdgcn_global_load_lds(
        (const __attribute__((address_space(1))) unsigned int*)g,
        (__attribute__((address_space(3))) unsigned int*)l, 16, 0, 0);
}

// ---------------------------------------------------------------------------
// Kernel 0: transpose+convert W (fp32 [k][n]) -> Wt (bf16 [n][k]); z==2 builds
// Wbt (bf16 [mid][d] = Wb^T). grid (16,16,3), block 256.
// ---------------------------------------------------------------------------
__global__ __launch_bounds__(256) void convert_w(
    fptr W0, fptr W1, fptr Wb, unsigned short* Wt0, unsigned short* Wt1,
    unsigned short* Wbt)
{
    __shared__ float tl[64][65];
    __shared__ unsigned short tb[8192];
    int t = threadIdx.x;
    if (blockIdx.z == 2) {
        if (blockIdx.x || blockIdx.y) return;
        for (int i = 0; i < 32; i++) {
            int idx = i * 256 + t;             // idx = d*64 + mid
            tb[(idx & 63) * 128 + (idx >> 6)] = f2b(Wb[idx]);
        }
        __syncthreads();
        for (int i = 0; i < 4; i++) {
            int o = (i * 256 + t) * 8;
            *(u16x8*)&Wbt[o] = *(const u16x8*)&tb[o];
        }
        return;
    }
    fptr W = blockIdx.z ? W1 : W0;
    unsigned short* Wt = blockIdx.z ? Wt1 : Wt0;
    int k0 = blockIdx.x * 64, n0 = blockIdx.y * 64;
    #pragma unroll
    for (int i = 0; i < 16; i++) {
        int kl = i * 4 + (t >> 6), nl = t & 63;
        tl[kl][nl] = W[(size_t)(k0 + kl) * 1024 + n0 + nl];
    }
    __syncthreads();
    #pragma unroll
    for (int i = 0; i < 16; i++) {
        int nl = i * 4 + (t >> 6), kl = t & 63;
        Wt[(size_t)(n0 + nl) * 1024 + k0 + kl] = f2b(tl[kl][nl]);
    }
}

// ---------------------------------------------------------------------------
// Kernel 0b: convert A fp32 -> bf16 contiguous. grid (16384), block 256.
// ---------------------------------------------------------------------------
__global__ __launch_bounds__(256) void convert_a(fptr A, unsigned short* B)
{
    size_t idx = ((size_t)blockIdx.x * 256 + threadIdx.x) * 8;
    const float4* ap = (const float4*)(A + idx);
    float4 a0 = ap[0], a1 = ap[1];
    u16x8 p = { f2b(a0.x), f2b(a0.y), f2b(a0.z), f2b(a0.w),
                f2b(a1.x), f2b(a1.y), f2b(a1.z), f2b(a1.w) };
    *(u16x8*)(B + idx) = p;
}

// ---------------------------------------------------------------------------
// Kernel 1: small in_proj (query->q, value1->v1), fp32 in/out (ws)
// ---------------------------------------------------------------------------
__global__ __launch_bounds__(256) void small_proj(
    fptr x0, fptr W0, fptr b0, fptr g0, fptr be0,
    fptr x1, fptr W1, fptr b1, fptr g1, fptr be1,
    float* out0, float* out1)
{
    __shared__ float xs[1024];
    __shared__ float part[2][128];
    __shared__ float r4[4][2];
    int hgrp = blockIdx.x;
    int row  = blockIdx.y;
    int which = blockIdx.z;
    fptr x  = which ? x1  : x0;
    fptr W  = which ? W1  : W0;
    fptr bi = which ? b1  : b0;
    fptr g  = which ? g1  : g0;
    fptr be = which ? be1 : be0;
    float* outp = which ? out1 : out0;
    int t = threadIdx.x, lane = t & 63, wv = t >> 6;
    for (int i = t; i < 1024; i += 256) xs[i] = x[row * 1024 + i];
    __syncthreads();
    int cl = t & 127, kh = t >> 7;
    int col = hgrp * 128 + cl;
    float acc = 0.f;
    const float* wp = W + (size_t)(kh * 512) * 1024 + col;
    for (int k = 0; k < 512; k++) acc += xs[kh * 512 + k] * wp[(size_t)k * 1024];
    part[kh][cl] = acc;
    __syncthreads();
    float e = 0.f;
    if (t < 128) e = elu_f(part[0][t] + part[1][t] + bi[col]);
    float s = e, ss = e * e;
    for (int m = 32; m > 0; m >>= 1) { s += __shfl_xor(s, m); ss += __shfl_xor(ss, m); }
    if (lane == 0) { r4[wv][0] = s; r4[wv][1] = ss; }
    __syncthreads();
    float S  = r4[0][0] + r4[1][0] + r4[2][0] + r4[3][0];
    float SS = r4[0][1] + r4[1][1] + r4[2][1] + r4[3][1];
    float mean = S * (1.f / 128.f);
    float var  = SS * (1.f / 128.f) - mean * mean;
    float inv  = rsqrtf(var + 1e-3f);
    if (t < 128) outp[row * 1024 + col] = (e - mean) * inv * g[col] + be[col];
}

// ---------------------------------------------------------------------------
// Kernel 1b: qwb[bh][mid][d] = Wbt[mid][d] * q[b,h,d]  (bf16). grid(128).
// ---------------------------------------------------------------------------
__global__ __launch_bounds__(256) void qwb_prep(
    bfp Wbt, const float* qws, unsigned short* qwbuf)
{
    int bh = blockIdx.x;
    int b = bh >> 3, h = bh & 7;
    int t = threadIdx.x;
    #pragma unroll
    for (int i = 0; i < 4; i++) {
        int idx = (i * 256 + t) * 8;       // elem index (8-aligned; 128%8==0)
        int d = idx & 127;
        u16x8 wv = *(const u16x8*)&Wbt[idx];
        const float* qp = qws + b * 1024 + h * 128 + d;
        u16x8 o;
        #pragma unroll
        for (int j = 0; j < 8; j++) o[j] = f2b(b2f(wv[j]) * qp[j]);
        *(u16x8*)&qwbuf[(size_t)bh * 8192 + idx] = o;
    }
}

// ---------------------------------------------------------------------------
// Kernel 2: K-GEMM + groupnorm + FUSED attn_basic.
// grid(256, 8): blockIdx.x = row tile (XCD swizzle), blockIdx.y = h = col tile.
// Phase 1: z = A @ WtK^T (BK=64 dbuf, m97 staging, verified).
// Phase 2: bias+elu+groupnorm -> normed tile into LDS (Tt, padded rows),
//          reusing the dead As/Bs staging space.
// Phase 3: basic = relu(Tt @ qwb^T + bb) via MFMA -> logits + poolpart
//          (exact attn_basic epilogue, verified R4/R5). zK never materialized.
// ---------------------------------------------------------------------------
__global__ __launch_bounds__(256) void gemm_k_attn(
    bfp A, bfp Wt, fptr bias, fptr g, fptr be,
    bfp qwb, fptr maskp, fptr bbp, fptr Wl1, fptr bl1,
    float* logits, float* poolpart)
{
    // 34816 B pool: As[2][128][32] (16 KB) + Bs[2][128][32] (16 KB) overlapped
    // by Tt[128][136] (34 KB) after the K-loop.
    __shared__ __align__(16) unsigned short pool[17408];
    unsigned short (*As)[128][32] = (unsigned short (*)[128][32])pool;
    unsigned short (*Bs)[128][32] = (unsigned short (*)[128][32])(pool + 8192);
    unsigned short (*Tt)[136]     = (unsigned short (*)[136])pool;
    __shared__ float sstat[128][2][2];
    __shared__ float masksh[128];
    __shared__ float poolred[4][64];

    int r0 = blockIdx.x * 128;     // global row tile (b*2048 + mloc)
    int h  = blockIdx.y;
    int n0 = h * 128;
    int b  = r0 >> 11;             // 2048 rows per batch
    int mloc = r0 & 2047;
    int mt = (r0 >> 7) & 15;
    int t = threadIdx.x, lane = t & 63, w = t >> 6;
    int c = lane & 15, q = lane >> 4;
    int rowbase = (w & 1) * 64, colbase = (w >> 1) * 64;

    if (t < 128) masksh[t] = maskp[r0 + t];

    f32x4 acc[4][4];
    const f32x4 fzero = {0.f, 0.f, 0.f, 0.f};
    #pragma unroll
    for (int i = 0; i < 4; i++)
        #pragma unroll
        for (int j = 0; j < 4; j++) acc[i][j] = fzero;

    int srow = lane >> 2;            // 0..15 within a 16-row issue
    int sseg = (lane & 3) * 8;       // k offset (8 bf16 = 16 B)
    const unsigned short* ag = A  + (size_t)(r0 + w * 32 + srow) * 1024 + sseg;
    const unsigned short* bg = Wt + (size_t)(n0 + w * 32 + srow) * 1024 + sseg;

    for (int k0 = 0; k0 < 1024; k0 += 64) {
        load_lds16(ag + k0,                  &As[0][w * 32][0]);
        load_lds16(ag + k0 + 16 * 1024,      &As[0][w * 32 + 16][0]);
        load_lds16(ag + k0 + 32,             &As[1][w * 32][0]);
        load_lds16(ag + k0 + 32 + 16 * 1024, &As[1][w * 32 + 16][0]);
        load_lds16(bg + k0,                  &Bs[0][w * 32][0]);
        load_lds16(bg + k0 + 16 * 1024,      &Bs[0][w * 32 + 16][0]);
        load_lds16(bg + k0 + 32,             &Bs[1][w * 32][0]);
        load_lds16(bg + k0 + 32 + 16 * 1024, &Bs[1][w * 32 + 16][0]);
        __syncthreads();
        #pragma unroll
        for (int p = 0; p < 2; p++) {
            bf16x8 af[4], bfv[4];
            #pragma unroll
            for (int i = 0; i < 4; i++) af[i]  = *(const bf16x8*)&As[p][rowbase + i * 16 + c][q * 8];
            #pragma unroll
            for (int j = 0; j < 4; j++) bfv[j] = *(const bf16x8*)&Bs[p][colbase + j * 16 + c][q * 8];
            #pragma unroll
            for (int i = 0; i < 4; i++)
                #pragma unroll
                for (int j = 0; j < 4; j++)
                    acc[i][j] = __builtin_amdgcn_mfma_f32_16x16x32_bf16(af[i], bfv[j], acc[i][j], 0, 0, 0);
        }
        __syncthreads();
    }

    // ---- phase 2: bias + elu + groupnorm stats (verified epilogue)
    float bcol[4], gcol[4], Bcol[4];
    #pragma unroll
    for (int j = 0; j < 4; j++) {
        int cg = n0 + colbase + j * 16 + c;
        bcol[j] = bias[cg]; gcol[j] = g[cg]; Bcol[j] = be[cg];
    }
    #pragma unroll
    for (int i = 0; i < 4; i++)
        #pragma unroll
        for (int j = 0; j < 4; j++)
            #pragma unroll
            for (int r = 0; r < 4; r++)
                acc[i][j][r] = elu_f(acc[i][j][r] + bcol[j]);
    #pragma unroll
    for (int i = 0; i < 4; i++) {
        #pragma unroll
        for (int r = 0; r < 4; r++) {
            float s  = acc[i][0][r] + acc[i][1][r] + acc[i][2][r] + acc[i][3][r];
            float ss = acc[i][0][r] * acc[i][0][r] + acc[i][1][r] * acc[i][1][r]
                     + acc[i][2][r] * acc[i][2][r] + acc[i][3][r] * acc[i][3][r];
            for (int m = 1; m < 16; m <<= 1) { s += __shfl_xor(s, m); ss += __shfl_xor(ss, m); }
            if (c == 0) {
                int rl = rowbase + i * 16 + q * 4 + r;
                sstat[rl][w >> 1][0] = s;
                sstat[rl][w >> 1][1] = ss;
            }
        }
    }
    __syncthreads();
    // normed tile -> Tt (LDS), bf16. As/Bs staging data is dead now.
    #pragma unroll
    for (int i = 0; i < 4; i++) {
        #pragma unroll
        for (int r = 0; r < 4; r++) {
            int rl = rowbase + i * 16 + q * 4 + r;
            float S  = sstat[rl][0][0] + sstat[rl][1][0];
            float SS = sstat[rl][0][1] + sstat[rl][1][1];
            float mean = S * (1.f / 128.f);
            float var  = SS * (1.f / 128.f) - mean * mean;
            float inv  = rsqrtf(var + 1e-3f);
            #pragma unroll
            for (int j = 0; j < 4; j++) {
                int cl = colbase + j * 16 + c;
                float v = (acc[i][j][r] - mean) * inv * gcol[j] + Bcol[j];
                Tt[rl][cl] = f2b(v);
            }
        }
    }
    __syncthreads();

    // ---- phase 3: attn MFMA (B-frags straight from global qwb; L2-hot)
    const unsigned short* qb = qwb + (size_t)(b * 8 + h) * 8192;
    f32x4 acc2[2][4];
    #pragma unroll
    for (int i = 0; i < 2; i++)
        #pragma unroll
        for (int j = 0; j < 4; j++) acc2[i][j] = fzero;
    #pragma unroll
    for (int s = 0; s < 4; s++) {
        bf16x8 af2[2], bfv[4];
        #pragma unroll
        for (int i = 0; i < 2; i++)
            af2[i] = *(const bf16x8*)&Tt[w * 32 + i * 16 + c][s * 32 + q * 8];
        #pragma unroll
        for (int j = 0; j < 4; j++)
            bfv[j] = *(const bf16x8*)&qb[(j * 16 + c) * 128 + s * 32 + q * 8];
        #pragma unroll
        for (int i = 0; i < 2; i++)
            #pragma unroll
            for (int j = 0; j < 4; j++)
                acc2[i][j] = __builtin_amdgcn_mfma_f32_16x16x32_bf16(af2[i], bfv[j], acc2[i][j], 0, 0, 0);
    }

    float bbs[4], wl1s[4];
    #pragma unroll
    for (int j = 0; j < 4; j++) { bbs[j] = bbp[j * 16 + c]; wl1s[j] = Wl1[j * 16 + c]; }
    float bl1v = bl1[0];
    float pp[4] = {0.f, 0.f, 0.f, 0.f};
    #pragma unroll
    for (int i = 0; i < 2; i++) {
        #pragma unroll
        for (int r = 0; r < 4; r++) {
            int ml = w * 32 + i * 16 + q * 4 + r;
            float mv = masksh[ml];
            float lg = 0.f;
            #pragma unroll
            for (int j = 0; j < 4; j++) {
                float basic = fmaxf(acc2[i][j][r] + bbs[j], 0.f);
                lg += basic * wl1s[j];
                pp[j] += basic * mv;
            }
            lg += __shfl_xor(lg, 1); lg += __shfl_xor(lg, 2);
            lg += __shfl_xor(lg, 4); lg += __shfl_xor(lg, 8);
            if (c == 0)
                logits[((size_t)(b * 8 + h)) * 2048 + mloc + ml] = lg + bl1v;
        }
    }
    #pragma unroll
    for (int j = 0; j < 4; j++) {
        pp[j] += __shfl_xor(pp[j], 16);
        pp[j] += __shfl_xor(pp[j], 32);
    }
    if (lane < 16) {
        #pragma unroll
        for (int j = 0; j < 4; j++) poolred[w][j * 16 + c] = pp[j];
    }
    __syncthreads();
    if (t < 64) {
        float p = poolred[0][t] + poolred[1][t] + poolred[2][t] + poolred[3][t];
        poolpart[((size_t)((b * 8 + h) * 16 + mt)) * 64 + t] = p;
    }
}

// ---------------------------------------------------------------------------
// Kernel 3 (V2): m97-style bf16 GEMM, BK=64 dbuf panels, XCD swizzle.
// Epilogue: bias + elu + groupnorm fused (verified). Z bf16.
// ---------------------------------------------------------------------------
__global__ __launch_bounds__(256) void mfma_gemm_bf(
    bfp A, bfp Wt, fptr bias, fptr g, fptr be, __hip_bfloat16* Z)
{
    __shared__ unsigned short As[2][128][32];
    __shared__ unsigned short Bs[2][128][32];
    __shared__ float sstat[128][2][2];
    int r0 = blockIdx.x * 128;     // row tile
    int n0 = blockIdx.y * 128;     // col tile
    int t = threadIdx.x, lane = t & 63, w = t >> 6;
    int c = lane & 15, q = lane >> 4;
    int rowbase = (w & 1) * 64, colbase = (w >> 1) * 64;

    f32x4 acc[4][4];
    const f32x4 fzero = {0.f, 0.f, 0.f, 0.f};
    #pragma unroll
    for (int i = 0; i < 4; i++)
        #pragma unroll
        for (int j = 0; j < 4; j++) acc[i][j] = fzero;

    int srow = lane >> 2;
    int sseg = (lane & 3) * 8;
    const unsigned short* ag = A  + (size_t)(r0 + w * 32 + srow) * 1024 + sseg;
    const unsigned short* bg = Wt + (size_t)(n0 + w * 32 + srow) * 1024 + sseg;

    for (int k0 = 0; k0 < 1024; k0 += 64) {
        load_lds16(ag + k0,                  &As[0][w * 32][0]);
        load_lds16(ag + k0 + 16 * 1024,      &As[0][w * 32 + 16][0]);
        load_lds16(ag + k0 + 32,             &As[1][w * 32][0]);
        load_lds16(ag + k0 + 32 + 16 * 1024, &As[1][w * 32 + 16][0]);
        load_lds16(bg + k0,                  &Bs[0][w * 32][0]);
        load_lds16(bg + k0 + 16 * 1024,      &Bs[0][w * 32 + 16][0]);
        load_lds16(bg + k0 + 32,             &Bs[1][w * 32][0]);
        load_lds16(bg + k0 + 32 + 16 * 1024, &Bs[1][w * 32 + 16][0]);
        __syncthreads();
        #pragma unroll
        for (int p = 0; p < 2; p++) {
            bf16x8 af[4], bfv[4];
            #pragma unroll
            for (int i = 0; i < 4; i++) af[i]  = *(const bf16x8*)&As[p][rowbase + i * 16 + c][q * 8];
            #pragma unroll
            for (int j = 0; j < 4; j++) bfv[j] = *(const bf16x8*)&Bs[p][colbase + j * 16 + c][q * 8];
            #pragma unroll
            for (int i = 0; i < 4; i++)
                #pragma unroll
                for (int j = 0; j < 4; j++)
                    acc[i][j] = __builtin_amdgcn_mfma_f32_16x16x32_bf16(af[i], bfv[j], acc[i][j], 0, 0, 0);
        }
        __syncthreads();
    }

    float bcol[4], gcol[4], Bcol[4];
    #pragma unroll
    for (int j = 0; j < 4; j++) {
        int cg = n0 + colbase + j * 16 + c;
        bcol[j] = bias[cg]; gcol[j] = g[cg]; Bcol[j] = be[cg];
    }
    #pragma unroll
    for (int i = 0; i < 4; i++)
        #pragma unroll
        for (int j = 0; j < 4; j++)
            #pragma unroll
            for (int r = 0; r < 4; r++)
                acc[i][j][r] = elu_f(acc[i][j][r] + bcol[j]);
    #pragma unroll
    for (int i = 0; i < 4; i++) {
        #pragma unroll
        for (int r = 0; r < 4; r++) {
            float s  = acc[i][0][r] + acc[i][1][r] + acc[i][2][r] + acc[i][3][r];
            float ss = acc[i][0][r] * acc[i][0][r] + acc[i][1][r] * acc[i][1][r]
                     + acc[i][2][r] * acc[i][2][r] + acc[i][3][r] * acc[i][3][r];
            for (int m = 1; m < 16; m <<= 1) { s += __shfl_xor(s, m); ss += __shfl_xor(ss, m); }
            if (c == 0) {
                int rl = rowbase + i * 16 + q * 4 + r;
                sstat[rl][w >> 1][0] = s;
                sstat[rl][w >> 1][1] = ss;
            }
        }
    }
    __syncthreads();
    #pragma unroll
    for (int i = 0; i < 4; i++) {
        #pragma unroll
        for (int r = 0; r < 4; r++) {
            int rl = rowbase + i * 16 + q * 4 + r;
            float S  = sstat[rl][0][0] + sstat[rl][1][0];
            float SS = sstat[rl][0][1] + sstat[rl][1][1];
            float mean = S * (1.f / 128.f);
            float var  = SS * (1.f / 128.f) - mean * mean;
            float inv  = rsqrtf(var + 1e-3f);
            #pragma unroll
            for (int j = 0; j < 4; j++) {
                int cg = n0 + colbase + j * 16 + c;
                float v = (acc[i][j][r] - mean) * inv * gcol[j] + Bcol[j];
                Z[(size_t)(r0 + rl) * 1024 + cg] = __float2bfloat16(v);
            }
        }
    }
}

// ---------------------------------------------------------------------------
// Kernel 4: FUSED softmax + pool + alpha_ch + v2 aggregation + output.
// grid (h=8, b=16), block 256. One block owns one (b,h).
// ---------------------------------------------------------------------------
__global__ __launch_bounds__(256) void finalize_fused(
    const float* logits, const float* poolpart, fptr maskp,
    const __hip_bfloat16* v2buf, const float* v1ws,
    fptr Wl2, fptr bl2, float* out)
{
    __shared__ float alph[2048];
    __shared__ float red[4];
    __shared__ float redm[4];
    __shared__ float pools[64];
    __shared__ float ach[128];
    __shared__ float redl[4][128];
    int h = blockIdx.x, b = blockIdx.y;
    int t = threadIdx.x, lane = t & 63, wv = t >> 6;

    // softmax over M (masked), normalized in LDS
    const float* lg = logits + (size_t)(b * 8 + h) * 2048;
    float msum_l = 0.f, mx_l = -1e30f;
    for (int i = t; i < 2048; i += 256) {
        float mv = maskp[b * 2048 + i];
        msum_l += mv;
        float v = (mv == 0.f) ? -1e9f : lg[i];
        alph[i] = v;
        mx_l = fmaxf(mx_l, v);
    }
    for (int mm = 32; mm > 0; mm >>= 1) {
        msum_l += __shfl_xor(msum_l, mm);
        mx_l = fmaxf(mx_l, __shfl_xor(mx_l, mm));
    }
    if (lane == 0) { red[wv] = msum_l; redm[wv] = mx_l; }
    __syncthreads();
    float msum = red[0] + red[1] + red[2] + red[3];
    float mx = fmaxf(fmaxf(redm[0], redm[1]), fmaxf(redm[2], redm[3]));

    float se = 0.f;
    for (int i = t; i < 2048; i += 256) {
        float e = expf(alph[i] - mx);   // same thread wrote alph[i]
        alph[i] = e;
        se += e;
    }
    for (int mm = 32; mm > 0; mm >>= 1) se += __shfl_xor(se, mm);
    __syncthreads();
    if (lane == 0) red[wv] = se;
    __syncthreads();
    float invS = 1.f / (red[0] + red[1] + red[2] + red[3]);
    for (int i = t; i < 2048; i += 256) alph[i] *= invS;

    // pool + alpha_ch
    if (t < 64) {
        const float* pq = poolpart + ((size_t)(b * 8 + h) * 16) * 64 + t;
        float p = 0.f;
        for (int pt = 0; pt < 16; pt++) p += pq[pt * 64];
        pools[t] = p / msum;
    }
    __syncthreads();
    if (t < 128) {
        float s2 = bl2[t];
        for (int mid = 0; mid < 64; mid++) s2 += pools[mid] * Wl2[mid * 128 + t];
        ach[t] = 1.f / (1.f + expf(-s2));
    }
    __syncthreads();

    // v2 aggregation over all 2048 m
    int mo = lane >> 4, d8 = (lane & 15) * 8;
    float acc[8] = {};
    for (int it = 0; it < 128; it++) {
        int m = it * 16 + wv * 4 + mo;
        bf16x8 v8 = *(const bf16x8*)&v2buf[((size_t)(b * 2048 + m)) * 1024 + h * 128 + d8];
        float a = alph[m];
        #pragma unroll
        for (int j = 0; j < 8; j++)
            acc[j] += a * b2f(((unsigned short*)&v8)[j]);
    }
    #pragma unroll
    for (int j = 0; j < 8; j++) {
        acc[j] += __shfl_xor(acc[j], 16);
        acc[j] += __shfl_xor(acc[j], 32);
    }
    if (lane < 16) {
        #pragma unroll
        for (int j = 0; j < 8; j++) redl[wv][d8 + j] = acc[j];
    }
    __syncthreads();
    if (t < 128) {
        float s = redl[0][t] + redl[1][t] + redl[2][t] + redl[3][t];
        out[b * 1024 + h * 128 + t] = v1ws[b * 1024 + h * 128 + t] * s * ach[t];
    }
}

// ---------------------------------------------------------------------------
extern "C" void kernel_launch(void* const* d_in, const int* in_sizes, int n_in,
                              void* d_out, int out_size, void* d_ws, size_t ws_size,
                              hipStream_t stream) {
    fptr query  = (fptr)d_in[0];
    fptr key    = (fptr)d_in[1];
    fptr maskp  = (fptr)d_in[2];
    fptr value1 = (fptr)d_in[3];
    fptr value2 = (fptr)d_in[4];
    fptr Wq = (fptr)d_in[5],  bq = (fptr)d_in[6],  gq = (fptr)d_in[7],  Bq = (fptr)d_in[8];
    fptr Wk = (fptr)d_in[9],  bk = (fptr)d_in[10], gk = (fptr)d_in[11], Bk = (fptr)d_in[12];
    fptr Wv1 = (fptr)d_in[13], bv1 = (fptr)d_in[14], gv1 = (fptr)d_in[15], Bv1 = (fptr)d_in[16];
    fptr Wv2 = (fptr)d_in[17], bv2 = (fptr)d_in[18], gv2 = (fptr)d_in[19], Bv2 = (fptr)d_in[20];
    fptr Wb = (fptr)d_in[21], bb = (fptr)d_in[22];
    fptr Wl1 = (fptr)d_in[23], bl1 = (fptr)d_in[24];
    fptr Wl2 = (fptr)d_in[25], bl2 = (fptr)d_in[26];

    const size_t MB = 1024 * 1024;
    char* w = (char*)d_ws;
    __hip_bfloat16* zV2 = (__hip_bfloat16*)w;                        // 0..64 MB
    unsigned short* Abf = (unsigned short*)(w + 64 * MB);            // 64..128 MB
    unsigned short* WtK  = (unsigned short*)(w + 128 * MB);          // 2 MB
    unsigned short* WtV2 = (unsigned short*)(w + 130 * MB);          // 2 MB
    unsigned short* Wbt  = (unsigned short*)(w + 132 * MB);          // 16 KB
    unsigned short* qwbuf = (unsigned short*)(w + 132 * MB + 65536); // 2 MB
    float* qws      = (float*)(w + 132 * MB + 65536 + 2 * MB);       // 64 KB
    float* v1ws     = qws + 16 * 1024;                               // 64 KB
    float* logits   = v1ws + 16 * 1024;                              // 1 MB
    float* poolpart = logits + 16 * 8 * 2048;                        // 512 KB  (-> ~136 MB total)
    float* out = (float*)d_out;

    hipLaunchKernelGGL(convert_w, dim3(16, 16, 3), dim3(256), 0, stream,
                       Wk, Wv2, Wb, WtK, WtV2, Wbt);
    hipLaunchKernelGGL(small_proj, dim3(8, 16, 2), dim3(256), 0, stream,
                       query, Wq, bq, gq, Bq, value1, Wv1, bv1, gv1, Bv1, qws, v1ws);
    hipLaunchKernelGGL(qwb_prep, dim3(128), dim3(256), 0, stream,
                       (bfp)Wbt, qws, qwbuf);
    hipLaunchKernelGGL(convert_a, dim3(16384), dim3(256), 0, stream, key, Abf);
    hipLaunchKernelGGL(gemm_k_attn, dim3(256, 8), dim3(256), 0, stream,
                       (bfp)Abf, (bfp)WtK, bk, gk, Bk,
                       (bfp)qwbuf, maskp, bb, Wl1, bl1, logits, poolpart);
    hipLaunchKernelGGL(convert_a, dim3(16384), dim3(256), 0, stream, value2, Abf);
    hipLaunchKernelGGL(mfma_gemm_bf, dim3(256, 8), dim3(256), 0, stream,
                       (bfp)Abf, (bfp)WtV2, bv2, gv2, Bv2, zV2);
    hipLaunchKernelGGL(finalize_fused, dim3(8, 16), dim3(256), 0, stream,
                       logits, poolpart, maskp, zV2, v1ws, Wl2, bl2, out);
}

// Round 7
// 643.390 us; speedup vs baseline: 1.1022x; 1.0668x over previous
//
#include <hip/hip_runtime.h>
#include <hip/hip_bf16.h>
#include <math.h>

typedef __attribute__((ext_vector_type(8))) short bf16x8;     // 8 bf16 = 4 VGPRs
typedef __attribute__((ext_vector_type(4))) float f32x4;      // MFMA accumulator
typedef __attribute__((ext_vector_type(8))) unsigned short u16x8;

typedef const float* fptr;
typedef const unsigned short* bfp;

__device__ inline float b2f(unsigned short u) {
    union { unsigned int i; float f; } v; v.i = ((unsigned int)u) << 16; return v.f;
}
__device__ inline unsigned short f2b(float x) {
    __hip_bfloat16 h = __float2bfloat16(x);
    return *(unsigned short*)&h;
}
__device__ inline float elu_f(float x) { return x > 0.f ? x : expm1f(x); }

// async global->LDS, 16 bytes per lane; lds dest = wave-uniform base + lane*16
__device__ inline void load_lds16(const void* g, void* l) {
    __builtin_amdgcn_global_load_lds(
        (const __attribute__((address_space(1))) unsigned int*)g,
        (__attribute__((address_space(3))) unsigned int*)l, 16, 0, 0);
}

// ---------------------------------------------------------------------------
// Kernel 0: transpose+convert W (fp32 [k][n]) -> Wt (bf16 [n][k]); z==2 builds
// Wbt (bf16 [mid][d] = Wb^T). grid (16,16,3), block 256.
// ---------------------------------------------------------------------------
__global__ __launch_bounds__(256) void convert_w(
    fptr W0, fptr W1, fptr Wb, unsigned short* Wt0, unsigned short* Wt1,
    unsigned short* Wbt)
{
    __shared__ float tl[64][65];
    __shared__ unsigned short tb[8192];
    int t = threadIdx.x;
    if (blockIdx.z == 2) {
        if (blockIdx.x || blockIdx.y) return;
        for (int i = 0; i < 32; i++) {
            int idx = i * 256 + t;             // idx = d*64 + mid
            tb[(idx & 63) * 128 + (idx >> 6)] = f2b(Wb[idx]);
        }
        __syncthreads();
        for (int i = 0; i < 4; i++) {
            int o = (i * 256 + t) * 8;
            *(u16x8*)&Wbt[o] = *(const u16x8*)&tb[o];
        }
        return;
    }
    fptr W = blockIdx.z ? W1 : W0;
    unsigned short* Wt = blockIdx.z ? Wt1 : Wt0;
    int k0 = blockIdx.x * 64, n0 = blockIdx.y * 64;
    #pragma unroll
    for (int i = 0; i < 16; i++) {
        int kl = i * 4 + (t >> 6), nl = t & 63;
        tl[kl][nl] = W[(size_t)(k0 + kl) * 1024 + n0 + nl];
    }
    __syncthreads();
    #pragma unroll
    for (int i = 0; i < 16; i++) {
        int nl = i * 4 + (t >> 6), kl = t & 63;
        Wt[(size_t)(n0 + nl) * 1024 + k0 + kl] = f2b(tl[kl][nl]);
    }
}

// ---------------------------------------------------------------------------
// Kernel 0b: convert key AND value2 fp32 -> bf16, one dispatch. grid (32768).
// ---------------------------------------------------------------------------
__global__ __launch_bounds__(256) void convert_a2(
    fptr A0, fptr A1, unsigned short* B0, unsigned short* B1)
{
    int blk = blockIdx.x;
    fptr A = (blk < 16384) ? A0 : A1;
    unsigned short* B = (blk < 16384) ? B0 : B1;
    size_t idx = ((size_t)(blk & 16383) * 256 + threadIdx.x) * 8;
    const float4* ap = (const float4*)(A + idx);
    float4 a0 = ap[0], a1 = ap[1];
    u16x8 p = { f2b(a0.x), f2b(a0.y), f2b(a0.z), f2b(a0.w),
                f2b(a1.x), f2b(a1.y), f2b(a1.z), f2b(a1.w) };
    *(u16x8*)(B + idx) = p;
}

// ---------------------------------------------------------------------------
// Kernel 1: small in_proj (query->q, value1->v1), fp32 in/out (ws)
// ---------------------------------------------------------------------------
__global__ __launch_bounds__(256) void small_proj(
    fptr x0, fptr W0, fptr b0, fptr g0, fptr be0,
    fptr x1, fptr W1, fptr b1, fptr g1, fptr be1,
    float* out0, float* out1)
{
    __shared__ float xs[1024];
    __shared__ float part[2][128];
    __shared__ float r4[4][2];
    int hgrp = blockIdx.x;
    int row  = blockIdx.y;
    int which = blockIdx.z;
    fptr x  = which ? x1  : x0;
    fptr W  = which ? W1  : W0;
    fptr bi = which ? b1  : b0;
    fptr g  = which ? g1  : g0;
    fptr be = which ? be1 : be0;
    float* outp = which ? out1 : out0;
    int t = threadIdx.x, lane = t & 63, wv = t >> 6;
    for (int i = t; i < 1024; i += 256) xs[i] = x[row * 1024 + i];
    __syncthreads();
    int cl = t & 127, kh = t >> 7;
    int col = hgrp * 128 + cl;
    float acc = 0.f;
    const float* wp = W + (size_t)(kh * 512) * 1024 + col;
    for (int k = 0; k < 512; k++) acc += xs[kh * 512 + k] * wp[(size_t)k * 1024];
    part[kh][cl] = acc;
    __syncthreads();
    float e = 0.f;
    if (t < 128) e = elu_f(part[0][t] + part[1][t] + bi[col]);
    float s = e, ss = e * e;
    for (int m = 32; m > 0; m >>= 1) { s += __shfl_xor(s, m); ss += __shfl_xor(ss, m); }
    if (lane == 0) { r4[wv][0] = s; r4[wv][1] = ss; }
    __syncthreads();
    float S  = r4[0][0] + r4[1][0] + r4[2][0] + r4[3][0];
    float SS = r4[0][1] + r4[1][1] + r4[2][1] + r4[3][1];
    float mean = S * (1.f / 128.f);
    float var  = SS * (1.f / 128.f) - mean * mean;
    float inv  = rsqrtf(var + 1e-3f);
    if (t < 128) outp[row * 1024 + col] = (e - mean) * inv * g[col] + be[col];
}

// ---------------------------------------------------------------------------
// Kernel 1b: qwb[bh][mid][d] = Wbt[mid][d] * q[b,h,d]  (bf16). grid(128).
// ---------------------------------------------------------------------------
__global__ __launch_bounds__(256) void qwb_prep(
    bfp Wbt, const float* qws, unsigned short* qwbuf)
{
    int bh = blockIdx.x;
    int b = bh >> 3, h = bh & 7;
    int t = threadIdx.x;
    #pragma unroll
    for (int i = 0; i < 4; i++) {
        int idx = (i * 256 + t) * 8;       // elem index (8-aligned; 128%8==0)
        int d = idx & 127;
        u16x8 wv = *(const u16x8*)&Wbt[idx];
        const float* qp = qws + b * 1024 + h * 128 + d;
        u16x8 o;
        #pragma unroll
        for (int j = 0; j < 8; j++) o[j] = f2b(b2f(wv[j]) * qp[j]);
        *(u16x8*)&qwbuf[(size_t)bh * 8192 + idx] = o;
    }
}

// ---------------------------------------------------------------------------
// Kernel 2: BOTH big GEMMs in one dispatch. grid(512, 8):
//   which = blockIdx.x >> 8 (0 = K-gemm + fused attn, 1 = V2-gemm -> zV2)
//   row tile = blockIdx.x & 255 (XCD swizzle preserved: 512 % 8 == 0)
// K-loop: m97 staging, BK=64 dbuf panels (verified R5/R6).
// Epilogue: bias+elu+groupnorm (verified R2-R6); which==0 additionally runs
// the attn MFMA phase (Tt in LDS reusing dead staging space; verified R6).
// __launch_bounds__(256,3): cap total regs ~170 -> 3 blocks/CU (was 2).
// ---------------------------------------------------------------------------
__global__ __launch_bounds__(256, 3) void gemm_fused(
    bfp AK, bfp WtK, fptr bkp, fptr gkp, fptr Bkp,
    bfp AV, bfp WtV, fptr bvp, fptr gvp, fptr Bvp,
    bfp qwb, fptr maskp, fptr bbp, fptr Wl1, fptr bl1,
    float* logits, float* poolpart, __hip_bfloat16* Z)
{
    __shared__ __align__(16) unsigned short pool[17408];
    unsigned short (*As)[128][32] = (unsigned short (*)[128][32])pool;
    unsigned short (*Bs)[128][32] = (unsigned short (*)[128][32])(pool + 8192);
    unsigned short (*Tt)[136]     = (unsigned short (*)[136])pool;
    __shared__ float sstat[128][2][2];
    __shared__ float masksh[128];
    __shared__ float poolred[4][64];

    int which = blockIdx.x >> 8;
    int r0 = (blockIdx.x & 255) * 128;   // global row tile (b*2048 + mloc)
    int h  = blockIdx.y;
    int n0 = h * 128;
    int b  = r0 >> 11;
    int mloc = r0 & 2047;
    int mt = (r0 >> 7) & 15;
    int t = threadIdx.x, lane = t & 63, w = t >> 6;
    int c = lane & 15, q = lane >> 4;
    int rowbase = (w & 1) * 64, colbase = (w >> 1) * 64;

    bfp A    = which ? AV  : AK;
    bfp Wt   = which ? WtV : WtK;
    fptr bias = which ? bvp : bkp;
    fptr g    = which ? gvp : gkp;
    fptr be   = which ? Bvp : Bkp;

    if (which == 0 && t < 128) masksh[t] = maskp[r0 + t];

    f32x4 acc[4][4];
    const f32x4 fzero = {0.f, 0.f, 0.f, 0.f};
    #pragma unroll
    for (int i = 0; i < 4; i++)
        #pragma unroll
        for (int j = 0; j < 4; j++) acc[i][j] = fzero;

    int srow = lane >> 2;            // 0..15 within a 16-row issue
    int sseg = (lane & 3) * 8;       // k offset (8 bf16 = 16 B)
    const unsigned short* ag = A  + (size_t)(r0 + w * 32 + srow) * 1024 + sseg;
    const unsigned short* bg = Wt + (size_t)(n0 + w * 32 + srow) * 1024 + sseg;

    for (int k0 = 0; k0 < 1024; k0 += 64) {
        load_lds16(ag + k0,                  &As[0][w * 32][0]);
        load_lds16(ag + k0 + 16 * 1024,      &As[0][w * 32 + 16][0]);
        load_lds16(ag + k0 + 32,             &As[1][w * 32][0]);
        load_lds16(ag + k0 + 32 + 16 * 1024, &As[1][w * 32 + 16][0]);
        load_lds16(bg + k0,                  &Bs[0][w * 32][0]);
        load_lds16(bg + k0 + 16 * 1024,      &Bs[0][w * 32 + 16][0]);
        load_lds16(bg + k0 + 32,             &Bs[1][w * 32][0]);
        load_lds16(bg + k0 + 32 + 16 * 1024, &Bs[1][w * 32 + 16][0]);
        __syncthreads();
        #pragma unroll
        for (int p = 0; p < 2; p++) {
            bf16x8 af[4], bfv[4];
            #pragma unroll
            for (int i = 0; i < 4; i++) af[i]  = *(const bf16x8*)&As[p][rowbase + i * 16 + c][q * 8];
            #pragma unroll
            for (int j = 0; j < 4; j++) bfv[j] = *(const bf16x8*)&Bs[p][colbase + j * 16 + c][q * 8];
            #pragma unroll
            for (int i = 0; i < 4; i++)
                #pragma unroll
                for (int j = 0; j < 4; j++)
                    acc[i][j] = __builtin_amdgcn_mfma_f32_16x16x32_bf16(af[i], bfv[j], acc[i][j], 0, 0, 0);
        }
        __syncthreads();
    }

    // ---- bias + elu + groupnorm stats (verified epilogue)
    float bcol[4], gcol[4], Bcol[4];
    #pragma unroll
    for (int j = 0; j < 4; j++) {
        int cg = n0 + colbase + j * 16 + c;
        bcol[j] = bias[cg]; gcol[j] = g[cg]; Bcol[j] = be[cg];
    }
    #pragma unroll
    for (int i = 0; i < 4; i++)
        #pragma unroll
        for (int j = 0; j < 4; j++)
            #pragma unroll
            for (int r = 0; r < 4; r++)
                acc[i][j][r] = elu_f(acc[i][j][r] + bcol[j]);
    #pragma unroll
    for (int i = 0; i < 4; i++) {
        #pragma unroll
        for (int r = 0; r < 4; r++) {
            float s  = acc[i][0][r] + acc[i][1][r] + acc[i][2][r] + acc[i][3][r];
            float ss = acc[i][0][r] * acc[i][0][r] + acc[i][1][r] * acc[i][1][r]
                     + acc[i][2][r] * acc[i][2][r] + acc[i][3][r] * acc[i][3][r];
            for (int m = 1; m < 16; m <<= 1) { s += __shfl_xor(s, m); ss += __shfl_xor(ss, m); }
            if (c == 0) {
                int rl = rowbase + i * 16 + q * 4 + r;
                sstat[rl][w >> 1][0] = s;
                sstat[rl][w >> 1][1] = ss;
            }
        }
    }
    __syncthreads();
    // normalize; which==0 -> Tt (LDS, staging space dead), which==1 -> Z
    #pragma unroll
    for (int i = 0; i < 4; i++) {
        #pragma unroll
        for (int r = 0; r < 4; r++) {
            int rl = rowbase + i * 16 + q * 4 + r;
            float S  = sstat[rl][0][0] + sstat[rl][1][0];
            float SS = sstat[rl][0][1] + sstat[rl][1][1];
            float mean = S * (1.f / 128.f);
            float var  = SS * (1.f / 128.f) - mean * mean;
            float inv  = rsqrtf(var + 1e-3f);
            #pragma unroll
            for (int j = 0; j < 4; j++) {
                int cl = colbase + j * 16 + c;
                float v = (acc[i][j][r] - mean) * inv * gcol[j] + Bcol[j];
                if (which == 0) Tt[rl][cl] = f2b(v);
                else Z[(size_t)(r0 + rl) * 1024 + n0 + cl] = __float2bfloat16(v);
            }
        }
    }
    if (which != 0) return;
    __syncthreads();

    // ---- attn phase (verified R6): basic = relu(Tt @ qwb^T + bb)
    const unsigned short* qb = qwb + (size_t)(b * 8 + h) * 8192;
    f32x4 acc2[2][4];
    #pragma unroll
    for (int i = 0; i < 2; i++)
        #pragma unroll
        for (int j = 0; j < 4; j++) acc2[i][j] = fzero;
    #pragma unroll
    for (int s = 0; s < 4; s++) {
        bf16x8 af2[2], bfv[4];
        #pragma unroll
        for (int i = 0; i < 2; i++)
            af2[i] = *(const bf16x8*)&Tt[w * 32 + i * 16 + c][s * 32 + q * 8];
        #pragma unroll
        for (int j = 0; j < 4; j++)
            bfv[j] = *(const bf16x8*)&qb[(j * 16 + c) * 128 + s * 32 + q * 8];
        #pragma unroll
        for (int i = 0; i < 2; i++)
            #pragma unroll
            for (int j = 0; j < 4; j++)
                acc2[i][j] = __builtin_amdgcn_mfma_f32_16x16x32_bf16(af2[i], bfv[j], acc2[i][j], 0, 0, 0);
    }

    float bbs[4], wl1s[4];
    #pragma unroll
    for (int j = 0; j < 4; j++) { bbs[j] = bbp[j * 16 + c]; wl1s[j] = Wl1[j * 16 + c]; }
    float bl1v = bl1[0];
    float pp[4] = {0.f, 0.f, 0.f, 0.f};
    #pragma unroll
    for (int i = 0; i < 2; i++) {
        #pragma unroll
        for (int r = 0; r < 4; r++) {
            int ml = w * 32 + i * 16 + q * 4 + r;
            float mv = masksh[ml];
            float lg = 0.f;
            #pragma unroll
            for (int j = 0; j < 4; j++) {
                float basic = fmaxf(acc2[i][j][r] + bbs[j], 0.f);
                lg += basic * wl1s[j];
                pp[j] += basic * mv;
            }
            lg += __shfl_xor(lg, 1); lg += __shfl_xor(lg, 2);
            lg += __shfl_xor(lg, 4); lg += __shfl_xor(lg, 8);
            if (c == 0)
                logits[((size_t)(b * 8 + h)) * 2048 + mloc + ml] = lg + bl1v;
        }
    }
    #pragma unroll
    for (int j = 0; j < 4; j++) {
        pp[j] += __shfl_xor(pp[j], 16);
        pp[j] += __shfl_xor(pp[j], 32);
    }
    if (lane < 16) {
        #pragma unroll
        for (int j = 0; j < 4; j++) poolred[w][j * 16 + c] = pp[j];
    }
    __syncthreads();
    if (t < 64) {
        float p = poolred[0][t] + poolred[1][t] + poolred[2][t] + poolred[3][t];
        poolpart[((size_t)((b * 8 + h) * 16 + mt)) * 64 + t] = p;
    }
}

// ---------------------------------------------------------------------------
// Kernel 3: FUSED softmax + pool + alpha_ch + v2 aggregation + output.
// grid (h=8, b=16), block 256. One block owns one (b,h).
// ---------------------------------------------------------------------------
__global__ __launch_bounds__(256) void finalize_fused(
    const float* logits, const float* poolpart, fptr maskp,
    const __hip_bfloat16* v2buf, const float* v1ws,
    fptr Wl2, fptr bl2, float* out)
{
    __shared__ float alph[2048];
    __shared__ float red[4];
    __shared__ float redm[4];
    __shared__ float pools[64];
    __shared__ float ach[128];
    __shared__ float redl[4][128];
    int h = blockIdx.x, b = blockIdx.y;
    int t = threadIdx.x, lane = t & 63, wv = t >> 6;

    const float* lg = logits + (size_t)(b * 8 + h) * 2048;
    float msum_l = 0.f, mx_l = -1e30f;
    for (int i = t; i < 2048; i += 256) {
        float mv = maskp[b * 2048 + i];
        msum_l += mv;
        float v = (mv == 0.f) ? -1e9f : lg[i];
        alph[i] = v;
        mx_l = fmaxf(mx_l, v);
    }
    for (int mm = 32; mm > 0; mm >>= 1) {
        msum_l += __shfl_xor(msum_l, mm);
        mx_l = fmaxf(mx_l, __shfl_xor(mx_l, mm));
    }
    if (lane == 0) { red[wv] = msum_l; redm[wv] = mx_l; }
    __syncthreads();
    float msum = red[0] + red[1] + red[2] + red[3];
    float mx = fmaxf(fmaxf(redm[0], redm[1]), fmaxf(redm[2], redm[3]));

    float se = 0.f;
    for (int i = t; i < 2048; i += 256) {
        float e = expf(alph[i] - mx);   // same thread wrote alph[i]
        alph[i] = e;
        se += e;
    }
    for (int mm = 32; mm > 0; mm >>= 1) se += __shfl_xor(se, mm);
    __syncthreads();
    if (lane == 0) red[wv] = se;
    __syncthreads();
    float invS = 1.f / (red[0] + red[1] + red[2] + red[3]);
    for (int i = t; i < 2048; i += 256) alph[i] *= invS;

    if (t < 64) {
        const float* pq = poolpart + ((size_t)(b * 8 + h) * 16) * 64 + t;
        float p = 0.f;
        for (int pt = 0; pt < 16; pt++) p += pq[pt * 64];
        pools[t] = p / msum;
    }
    __syncthreads();
    if (t < 128) {
        float s2 = bl2[t];
        for (int mid = 0; mid < 64; mid++) s2 += pools[mid] * Wl2[mid * 128 + t];
        ach[t] = 1.f / (1.f + expf(-s2));
    }
    __syncthreads();

    int mo = lane >> 4, d8 = (lane & 15) * 8;
    float acc[8] = {};
    for (int it = 0; it < 128; it++) {
        int m = it * 16 + wv * 4 + mo;
        bf16x8 v8 = *(const bf16x8*)&v2buf[((size_t)(b * 2048 + m)) * 1024 + h * 128 + d8];
        float a = alph[m];
        #pragma unroll
        for (int j = 0; j < 8; j++)
            acc[j] += a * b2f(((unsigned short*)&v8)[j]);
    }
    #pragma unroll
    for (int j = 0; j < 8; j++) {
        acc[j] += __shfl_xor(acc[j], 16);
        acc[j] += __shfl_xor(acc[j], 32);
    }
    if (lane < 16) {
        #pragma unroll
        for (int j = 0; j < 8; j++) redl[wv][d8 + j] = acc[j];
    }
    __syncthreads();
    if (t < 128) {
        float s = redl[0][t] + redl[1][t] + redl[2][t] + redl[3][t];
        out[b * 1024 + h * 128 + t] = v1ws[b * 1024 + h * 128 + t] * s * ach[t];
    }
}

// ---------------------------------------------------------------------------
extern "C" void kernel_launch(void* const* d_in, const int* in_sizes, int n_in,
                              void* d_out, int out_size, void* d_ws, size_t ws_size,
                              hipStream_t stream) {
    fptr query  = (fptr)d_in[0];
    fptr key    = (fptr)d_in[1];
    fptr maskp  = (fptr)d_in[2];
    fptr value1 = (fptr)d_in[3];
    fptr value2 = (fptr)d_in[4];
    fptr Wq = (fptr)d_in[5],  bq = (fptr)d_in[6],  gq = (fptr)d_in[7],  Bq = (fptr)d_in[8];
    fptr Wk = (fptr)d_in[9],  bk = (fptr)d_in[10], gk = (fptr)d_in[11], Bk = (fptr)d_in[12];
    fptr Wv1 = (fptr)d_in[13], bv1 = (fptr)d_in[14], gv1 = (fptr)d_in[15], Bv1 = (fptr)d_in[16];
    fptr Wv2 = (fptr)d_in[17], bv2 = (fptr)d_in[18], gv2 = (fptr)d_in[19], Bv2 = (fptr)d_in[20];
    fptr Wb = (fptr)d_in[21], bb = (fptr)d_in[22];
    fptr Wl1 = (fptr)d_in[23], bl1 = (fptr)d_in[24];
    fptr Wl2 = (fptr)d_in[25], bl2 = (fptr)d_in[26];

    const size_t MB = 1024 * 1024;
    char* w = (char*)d_ws;
    unsigned short* AbfK  = (unsigned short*)w;                      // 0..64 MB
    unsigned short* AbfV2 = (unsigned short*)(w + 64 * MB);          // 64..128 MB
    __hip_bfloat16* zV2   = (__hip_bfloat16*)(w + 128 * MB);         // 128..192 MB
    unsigned short* WtK   = (unsigned short*)(w + 192 * MB);         // 2 MB
    unsigned short* WtV2  = (unsigned short*)(w + 194 * MB);         // 2 MB
    unsigned short* Wbt   = (unsigned short*)(w + 196 * MB);         // 16 KB
    unsigned short* qwbuf = (unsigned short*)(w + 196 * MB + 65536); // 2 MB
    float* qws      = (float*)(w + 196 * MB + 65536 + 2 * MB);       // 64 KB
    float* v1ws     = qws + 16 * 1024;                               // 64 KB
    float* logits   = v1ws + 16 * 1024;                              // 1 MB
    float* poolpart = logits + 16 * 8 * 2048;                        // 512 KB (-> <200 MB total)
    float* out = (float*)d_out;

    hipLaunchKernelGGL(convert_w, dim3(16, 16, 3), dim3(256), 0, stream,
                       Wk, Wv2, Wb, WtK, WtV2, Wbt);
    hipLaunchKernelGGL(small_proj, dim3(8, 16, 2), dim3(256), 0, stream,
                       query, Wq, bq, gq, Bq, value1, Wv1, bv1, gv1, Bv1, qws, v1ws);
    hipLaunchKernelGGL(qwb_prep, dim3(128), dim3(256), 0, stream,
                       (bfp)Wbt, qws, qwbuf);
    hipLaunchKernelGGL(convert_a2, dim3(32768), dim3(256), 0, stream,
                       key, value2, AbfK, AbfV2);
    hipLaunchKernelGGL(gemm_fused, dim3(512, 8), dim3(256), 0, stream,
                       (bfp)AbfK, (bfp)WtK, bk, gk, Bk,
                       (bfp)AbfV2, (bfp)WtV2, bv2, gv2, Bv2,
                       (bfp)qwbuf, maskp, bb, Wl1, bl1, logits, poolpart, zV2);
    hipLaunchKernelGGL(finalize_fused, dim3(8, 16), dim3(256), 0, stream,
                       logits, poolpart, maskp, zV2, v1ws, Wl2, bl2, out);
}

// Round 8
// 602.490 us; speedup vs baseline: 1.1770x; 1.0679x over previous
//
#include <hip/hip_runtime.h>
#include <hip/hip_bf16.h>
#include <math.h>

typedef __attribute__((ext_vector_type(8))) short bf16x8;     // 8 bf16 = 4 VGPRs
typedef __attribute__((ext_vector_type(4))) float f32x4;      // MFMA accumulator
typedef __attribute__((ext_vector_type(8))) unsigned short u16x8;

typedef const float* fptr;
typedef const unsigned short* bfp;

__device__ inline float b2f(unsigned short u) {
    union { unsigned int i; float f; } v; v.i = ((unsigned int)u) << 16; return v.f;
}
__device__ inline unsigned short f2b(float x) {
    __hip_bfloat16 h = __float2bfloat16(x);
    return *(unsigned short*)&h;
}
// fast elu: __expf -> v_exp_f32 sequence; |err| ~1e-7 absolute near 0, fine for bf16-level outputs
__device__ inline float elu_f(float x) { return x > 0.f ? x : __expf(x) - 1.f; }

// async global->LDS, 16 bytes per lane; lds dest = wave-uniform base + lane*16
__device__ inline void load_lds16(const void* g, void* l) {
    __builtin_amdgcn_global_load_lds(
        (const __attribute__((address_space(1))) unsigned int*)g,
        (__attribute__((address_space(3))) unsigned int*)l, 16, 0, 0);
}

// ---------------------------------------------------------------------------
// Kernel 0 (MERGED PREP): one dispatch, grid 33537, blockIdx-partitioned:
//   [0, 32768)      convert key/value2 fp32 -> bf16 (AbfK / AbfV2)
//   [32768, 33280)  transpose+convert Wk/Wv2 -> WtK/WtV2 (bf16 [n][k])
//   33280           Wbt = Wb^T (bf16 [mid][d])
//   [33281, 33537)  small in_proj (query->qws, value1->v1ws)
// All parts independent; memory-bound cvt overlaps compute-bound small_proj.
// ---------------------------------------------------------------------------
__global__ __launch_bounds__(256) void prep(
    fptr key, fptr value2, unsigned short* AbfK, unsigned short* AbfV2,
    fptr Wk, fptr Wv2, unsigned short* WtK, unsigned short* WtV2,
    fptr Wb, unsigned short* Wbt,
    fptr query, fptr Wq, fptr bq, fptr gq, fptr Bq,
    fptr value1, fptr Wv1, fptr bv1, fptr gv1, fptr Bv1,
    float* qws, float* v1ws)
{
    __shared__ __align__(16) char smem[16640];
    int blk = blockIdx.x, t = threadIdx.x;

    if (blk < 32768) {                       // ---- convert_a2
        fptr A = (blk < 16384) ? key : value2;
        unsigned short* B = (blk < 16384) ? AbfK : AbfV2;
        size_t idx = ((size_t)(blk & 16383) * 256 + t) * 8;
        const float4* ap = (const float4*)(A + idx);
        float4 a0 = ap[0], a1 = ap[1];
        u16x8 p = { f2b(a0.x), f2b(a0.y), f2b(a0.z), f2b(a0.w),
                    f2b(a1.x), f2b(a1.y), f2b(a1.z), f2b(a1.w) };
        *(u16x8*)(B + idx) = p;
        return;
    }
    if (blk < 33280) {                       // ---- convert_w (transpose)
        float (*tl)[65] = (float (*)[65])smem;
        int idx = blk - 32768;
        fptr W = (idx >> 8) ? Wv2 : Wk;
        unsigned short* Wt = (idx >> 8) ? WtV2 : WtK;
        int k0 = ((idx >> 4) & 15) * 64, n0 = (idx & 15) * 64;
        #pragma unroll
        for (int i = 0; i < 16; i++) {
            int kl = i * 4 + (t >> 6), nl = t & 63;
            tl[kl][nl] = W[(size_t)(k0 + kl) * 1024 + n0 + nl];
        }
        __syncthreads();
        #pragma unroll
        for (int i = 0; i < 16; i++) {
            int nl = i * 4 + (t >> 6), kl = t & 63;
            Wt[(size_t)(n0 + nl) * 1024 + k0 + kl] = f2b(tl[kl][nl]);
        }
        return;
    }
    if (blk == 33280) {                      // ---- Wbt
        unsigned short* tb = (unsigned short*)smem;
        for (int i = 0; i < 32; i++) {
            int idx = i * 256 + t;           // idx = d*64 + mid
            tb[(idx & 63) * 128 + (idx >> 6)] = f2b(Wb[idx]);
        }
        __syncthreads();
        for (int i = 0; i < 4; i++) {
            int o = (i * 256 + t) * 8;
            *(u16x8*)&Wbt[o] = *(const u16x8*)&tb[o];
        }
        return;
    }
    // ---- small_proj
    {
        float* xs = (float*)smem;                      // 1024 f32
        float (*part)[128] = (float (*)[128])(smem + 4096);
        float (*r4)[2] = (float (*)[2])(smem + 4096 + 1024);
        int idx = blk - 33281;
        int hgrp = idx & 7;
        int row  = (idx >> 3) & 15;
        int which = idx >> 7;
        fptr x  = which ? value1 : query;
        fptr W  = which ? Wv1 : Wq;
        fptr bi = which ? bv1 : bq;
        fptr g  = which ? gv1 : gq;
        fptr be = which ? Bv1 : Bq;
        float* outp = which ? v1ws : qws;
        int lane = t & 63, wv = t >> 6;
        for (int i = t; i < 1024; i += 256) xs[i] = x[row * 1024 + i];
        __syncthreads();
        int cl = t & 127, kh = t >> 7;
        int col = hgrp * 128 + cl;
        float acc = 0.f;
        const float* wp = W + (size_t)(kh * 512) * 1024 + col;
        for (int k = 0; k < 512; k++) acc += xs[kh * 512 + k] * wp[(size_t)k * 1024];
        part[kh][cl] = acc;
        __syncthreads();
        float e = 0.f;
        if (t < 128) e = elu_f(part[0][t] + part[1][t] + bi[col]);
        float s = e, ss = e * e;
        for (int m = 32; m > 0; m >>= 1) { s += __shfl_xor(s, m); ss += __shfl_xor(ss, m); }
        if (lane == 0) { r4[wv][0] = s; r4[wv][1] = ss; }
        __syncthreads();
        float S  = r4[0][0] + r4[1][0] + r4[2][0] + r4[3][0];
        float SS = r4[0][1] + r4[1][1] + r4[2][1] + r4[3][1];
        float mean = S * (1.f / 128.f);
        float var  = SS * (1.f / 128.f) - mean * mean;
        float inv  = rsqrtf(var + 1e-3f);
        if (t < 128) outp[row * 1024 + col] = (e - mean) * inv * g[col] + be[col];
    }
}

// ---------------------------------------------------------------------------
// Kernel 1b: qwb[bh][mid][d] = Wbt[mid][d] * q[b,h,d]  (bf16). grid(128).
// ---------------------------------------------------------------------------
__global__ __launch_bounds__(256) void qwb_prep(
    bfp Wbt, const float* qws, unsigned short* qwbuf)
{
    int bh = blockIdx.x;
    int b = bh >> 3, h = bh & 7;
    int t = threadIdx.x;
    #pragma unroll
    for (int i = 0; i < 4; i++) {
        int idx = (i * 256 + t) * 8;       // elem index (8-aligned; 128%8==0)
        int d = idx & 127;
        u16x8 wv = *(const u16x8*)&Wbt[idx];
        const float* qp = qws + b * 1024 + h * 128 + d;
        u16x8 o;
        #pragma unroll
        for (int j = 0; j < 8; j++) o[j] = f2b(b2f(wv[j]) * qp[j]);
        *(u16x8*)&qwbuf[(size_t)bh * 8192 + idx] = o;
    }
}

// ---------------------------------------------------------------------------
// Kernel 2: BOTH big GEMMs in one dispatch. grid(512, 8):
//   which = blockIdx.x >> 8 (0 = K-gemm + fused attn, 1 = V2-gemm -> zV2)
//   row tile = blockIdx.x & 255 (XCD swizzle preserved: 512 % 8 == 0)
// K-loop: m97 staging, BK=64 dbuf panels (verified R5-R7).
// Epilogue: bias+elu+groupnorm (verified); which==0 adds attn MFMA phase.
// __launch_bounds__(256,3): 3 blocks/CU (verified R7: occupancy 32%).
// ---------------------------------------------------------------------------
__global__ __launch_bounds__(256, 3) void gemm_fused(
    bfp AK, bfp WtK, fptr bkp, fptr gkp, fptr Bkp,
    bfp AV, bfp WtV, fptr bvp, fptr gvp, fptr Bvp,
    bfp qwb, fptr maskp, fptr bbp, fptr Wl1, fptr bl1,
    float* logits, float* poolpart, __hip_bfloat16* Z)
{
    __shared__ __align__(16) unsigned short pool[17408];
    unsigned short (*As)[128][32] = (unsigned short (*)[128][32])pool;
    unsigned short (*Bs)[128][32] = (unsigned short (*)[128][32])(pool + 8192);
    unsigned short (*Tt)[136]     = (unsigned short (*)[136])pool;
    __shared__ float sstat[128][2][2];
    __shared__ float masksh[128];
    __shared__ float poolred[4][64];

    int which = blockIdx.x >> 8;
    int r0 = (blockIdx.x & 255) * 128;   // global row tile (b*2048 + mloc)
    int h  = blockIdx.y;
    int n0 = h * 128;
    int b  = r0 >> 11;
    int mloc = r0 & 2047;
    int mt = (r0 >> 7) & 15;
    int t = threadIdx.x, lane = t & 63, w = t >> 6;
    int c = lane & 15, q = lane >> 4;
    int rowbase = (w & 1) * 64, colbase = (w >> 1) * 64;

    bfp A    = which ? AV  : AK;
    bfp Wt   = which ? WtV : WtK;
    fptr bias = which ? bvp : bkp;
    fptr g    = which ? gvp : gkp;
    fptr be   = which ? Bvp : Bkp;

    if (which == 0 && t < 128) masksh[t] = maskp[r0 + t];

    f32x4 acc[4][4];
    const f32x4 fzero = {0.f, 0.f, 0.f, 0.f};
    #pragma unroll
    for (int i = 0; i < 4; i++)
        #pragma unroll
        for (int j = 0; j < 4; j++) acc[i][j] = fzero;

    int srow = lane >> 2;            // 0..15 within a 16-row issue
    int sseg = (lane & 3) * 8;       // k offset (8 bf16 = 16 B)
    const unsigned short* ag = A  + (size_t)(r0 + w * 32 + srow) * 1024 + sseg;
    const unsigned short* bg = Wt + (size_t)(n0 + w * 32 + srow) * 1024 + sseg;

    for (int k0 = 0; k0 < 1024; k0 += 64) {
        load_lds16(ag + k0,                  &As[0][w * 32][0]);
        load_lds16(ag + k0 + 16 * 1024,      &As[0][w * 32 + 16][0]);
        load_lds16(ag + k0 + 32,             &As[1][w * 32][0]);
        load_lds16(ag + k0 + 32 + 16 * 1024, &As[1][w * 32 + 16][0]);
        load_lds16(bg + k0,                  &Bs[0][w * 32][0]);
        load_lds16(bg + k0 + 16 * 1024,      &Bs[0][w * 32 + 16][0]);
        load_lds16(bg + k0 + 32,             &Bs[1][w * 32][0]);
        load_lds16(bg + k0 + 32 + 16 * 1024, &Bs[1][w * 32 + 16][0]);
        __syncthreads();
        #pragma unroll
        for (int p = 0; p < 2; p++) {
            bf16x8 af[4], bfv[4];
            #pragma unroll
            for (int i = 0; i < 4; i++) af[i]  = *(const bf16x8*)&As[p][rowbase + i * 16 + c][q * 8];
            #pragma unroll
            for (int j = 0; j < 4; j++) bfv[j] = *(const bf16x8*)&Bs[p][colbase + j * 16 + c][q * 8];
            #pragma unroll
            for (int i = 0; i < 4; i++)
                #pragma unroll
                for (int j = 0; j < 4; j++)
                    acc[i][j] = __builtin_amdgcn_mfma_f32_16x16x32_bf16(af[i], bfv[j], acc[i][j], 0, 0, 0);
        }
        __syncthreads();
    }

    // ---- bias + elu + groupnorm stats (verified epilogue)
    float bcol[4], gcol[4], Bcol[4];
    #pragma unroll
    for (int j = 0; j < 4; j++) {
        int cg = n0 + colbase + j * 16 + c;
        bcol[j] = bias[cg]; gcol[j] = g[cg]; Bcol[j] = be[cg];
    }
    #pragma unroll
    for (int i = 0; i < 4; i++)
        #pragma unroll
        for (int j = 0; j < 4; j++)
            #pragma unroll
            for (int r = 0; r < 4; r++)
                acc[i][j][r] = elu_f(acc[i][j][r] + bcol[j]);
    #pragma unroll
    for (int i = 0; i < 4; i++) {
        #pragma unroll
        for (int r = 0; r < 4; r++) {
            float s  = acc[i][0][r] + acc[i][1][r] + acc[i][2][r] + acc[i][3][r];
            float ss = acc[i][0][r] * acc[i][0][r] + acc[i][1][r] * acc[i][1][r]
                     + acc[i][2][r] * acc[i][2][r] + acc[i][3][r] * acc[i][3][r];
            for (int m = 1; m < 16; m <<= 1) { s += __shfl_xor(s, m); ss += __shfl_xor(ss, m); }
            if (c == 0) {
                int rl = rowbase + i * 16 + q * 4 + r;
                sstat[rl][w >> 1][0] = s;
                sstat[rl][w >> 1][1] = ss;
            }
        }
    }
    __syncthreads();
    // normalize; which==0 -> Tt (LDS, staging space dead), which==1 -> Z
    #pragma unroll
    for (int i = 0; i < 4; i++) {
        #pragma unroll
        for (int r = 0; r < 4; r++) {
            int rl = rowbase + i * 16 + q * 4 + r;
            float S  = sstat[rl][0][0] + sstat[rl][1][0];
            float SS = sstat[rl][0][1] + sstat[rl][1][1];
            float mean = S * (1.f / 128.f);
            float var  = SS * (1.f / 128.f) - mean * mean;
            float inv  = rsqrtf(var + 1e-3f);
            #pragma unroll
            for (int j = 0; j < 4; j++) {
                int cl = colbase + j * 16 + c;
                float v = (acc[i][j][r] - mean) * inv * gcol[j] + Bcol[j];
                if (which == 0) Tt[rl][cl] = f2b(v);
                else Z[(size_t)(r0 + rl) * 1024 + n0 + cl] = __float2bfloat16(v);
            }
        }
    }
    if (which != 0) return;
    __syncthreads();

    // ---- attn phase (verified R6/R7): basic = relu(Tt @ qwb^T + bb)
    const unsigned short* qb = qwb + (size_t)(b * 8 + h) * 8192;
    f32x4 acc2[2][4];
    #pragma unroll
    for (int i = 0; i < 2; i++)
        #pragma unroll
        for (int j = 0; j < 4; j++) acc2[i][j] = fzero;
    #pragma unroll
    for (int s = 0; s < 4; s++) {
        bf16x8 af2[2], bfv[4];
        #pragma unroll
        for (int i = 0; i < 2; i++)
            af2[i] = *(const bf16x8*)&Tt[w * 32 + i * 16 + c][s * 32 + q * 8];
        #pragma unroll
        for (int j = 0; j < 4; j++)
            bfv[j] = *(const bf16x8*)&qb[(j * 16 + c) * 128 + s * 32 + q * 8];
        #pragma unroll
        for (int i = 0; i < 2; i++)
            #pragma unroll
            for (int j = 0; j < 4; j++)
                acc2[i][j] = __builtin_amdgcn_mfma_f32_16x16x32_bf16(af2[i], bfv[j], acc2[i][j], 0, 0, 0);
    }

    float bbs[4], wl1s[4];
    #pragma unroll
    for (int j = 0; j < 4; j++) { bbs[j] = bbp[j * 16 + c]; wl1s[j] = Wl1[j * 16 + c]; }
    float bl1v = bl1[0];
    float pp[4] = {0.f, 0.f, 0.f, 0.f};
    #pragma unroll
    for (int i = 0; i < 2; i++) {
        #pragma unroll
        for (int r = 0; r < 4; r++) {
            int ml = w * 32 + i * 16 + q * 4 + r;
            float mv = masksh[ml];
            float lg = 0.f;
            #pragma unroll
            for (int j = 0; j < 4; j++) {
                float basic = fmaxf(acc2[i][j][r] + bbs[j], 0.f);
                lg += basic * wl1s[j];
                pp[j] += basic * mv;
            }
            lg += __shfl_xor(lg, 1); lg += __shfl_xor(lg, 2);
            lg += __shfl_xor(lg, 4); lg += __shfl_xor(lg, 8);
            if (c == 0)
                logits[((size_t)(b * 8 + h)) * 2048 + mloc + ml] = lg + bl1v;
        }
    }
    #pragma unroll
    for (int j = 0; j < 4; j++) {
        pp[j] += __shfl_xor(pp[j], 16);
        pp[j] += __shfl_xor(pp[j], 32);
    }
    if (lane < 16) {
        #pragma unroll
        for (int j = 0; j < 4; j++) poolred[w][j * 16 + c] = pp[j];
    }
    __syncthreads();
    if (t < 64) {
        float p = poolred[0][t] + poolred[1][t] + poolred[2][t] + poolred[3][t];
        poolpart[((size_t)((b * 8 + h) * 16 + mt)) * 64 + t] = p;
    }
}

// ---------------------------------------------------------------------------
// Kernel 3: FUSED softmax + pool + alpha_ch + v2 aggregation + output.
// grid (h=8, b=16), block 512 (8 waves: 2x latency hiding on the v2 read).
// ---------------------------------------------------------------------------
__global__ __launch_bounds__(512) void finalize_fused(
    const float* logits, const float* poolpart, fptr maskp,
    const __hip_bfloat16* v2buf, const float* v1ws,
    fptr Wl2, fptr bl2, float* out)
{
    __shared__ float alph[2048];
    __shared__ float red[8];
    __shared__ float redm[8];
    __shared__ float pools[64];
    __shared__ float ach[128];
    __shared__ float redl[8][128];
    int h = blockIdx.x, b = blockIdx.y;
    int t = threadIdx.x, lane = t & 63, wv = t >> 6;

    const float* lg = logits + (size_t)(b * 8 + h) * 2048;
    float msum_l = 0.f, mx_l = -1e30f;
    for (int i = t; i < 2048; i += 512) {
        float mv = maskp[b * 2048 + i];
        msum_l += mv;
        float v = (mv == 0.f) ? -1e9f : lg[i];
        alph[i] = v;
        mx_l = fmaxf(mx_l, v);
    }
    for (int mm = 32; mm > 0; mm >>= 1) {
        msum_l += __shfl_xor(msum_l, mm);
        mx_l = fmaxf(mx_l, __shfl_xor(mx_l, mm));
    }
    if (lane == 0) { red[wv] = msum_l; redm[wv] = mx_l; }
    __syncthreads();
    float msum = 0.f, mx = -1e30f;
    #pragma unroll
    for (int i = 0; i < 8; i++) { msum += red[i]; mx = fmaxf(mx, redm[i]); }

    float se = 0.f;
    for (int i = t; i < 2048; i += 512) {
        float e = __expf(alph[i] - mx);   // same thread wrote alph[i]
        alph[i] = e;
        se += e;
    }
    for (int mm = 32; mm > 0; mm >>= 1) se += __shfl_xor(se, mm);
    __syncthreads();
    if (lane == 0) red[wv] = se;
    __syncthreads();
    float S = 0.f;
    #pragma unroll
    for (int i = 0; i < 8; i++) S += red[i];
    float invS = 1.f / S;
    for (int i = t; i < 2048; i += 512) alph[i] *= invS;

    if (t < 64) {
        const float* pq = poolpart + ((size_t)(b * 8 + h) * 16) * 64 + t;
        float p = 0.f;
        for (int pt = 0; pt < 16; pt++) p += pq[pt * 64];
        pools[t] = p / msum;
    }
    __syncthreads();
    if (t < 128) {
        float s2 = bl2[t];
        for (int mid = 0; mid < 64; mid++) s2 += pools[mid] * Wl2[mid * 128 + t];
        ach[t] = 1.f / (1.f + __expf(-s2));
    }
    __syncthreads();

    // v2 aggregation over 2048 m: 8 waves x 4 m-rows per iter = 32 m/iter
    int mo = lane >> 4, d8 = (lane & 15) * 8;
    float acc[8] = {};
    for (int it = 0; it < 64; it++) {
        int m = it * 32 + wv * 4 + mo;
        bf16x8 v8 = *(const bf16x8*)&v2buf[((size_t)(b * 2048 + m)) * 1024 + h * 128 + d8];
        float a = alph[m];
        #pragma unroll
        for (int j = 0; j < 8; j++)
            acc[j] += a * b2f(((unsigned short*)&v8)[j]);
    }
    #pragma unroll
    for (int j = 0; j < 8; j++) {
        acc[j] += __shfl_xor(acc[j], 16);
        acc[j] += __shfl_xor(acc[j], 32);
    }
    if (lane < 16) {
        #pragma unroll
        for (int j = 0; j < 8; j++) redl[wv][d8 + j] = acc[j];
    }
    __syncthreads();
    if (t < 128) {
        float s = 0.f;
        #pragma unroll
        for (int i = 0; i < 8; i++) s += redl[i][t];
        out[b * 1024 + h * 128 + t] = v1ws[b * 1024 + h * 128 + t] * s * ach[t];
    }
}

// ---------------------------------------------------------------------------
extern "C" void kernel_launch(void* const* d_in, const int* in_sizes, int n_in,
                              void* d_out, int out_size, void* d_ws, size_t ws_size,
                              hipStream_t stream) {
    fptr query  = (fptr)d_in[0];
    fptr key    = (fptr)d_in[1];
    fptr maskp  = (fptr)d_in[2];
    fptr value1 = (fptr)d_in[3];
    fptr value2 = (fptr)d_in[4];
    fptr Wq = (fptr)d_in[5],  bq = (fptr)d_in[6],  gq = (fptr)d_in[7],  Bq = (fptr)d_in[8];
    fptr Wk = (fptr)d_in[9],  bk = (fptr)d_in[10], gk = (fptr)d_in[11], Bk = (fptr)d_in[12];
    fptr Wv1 = (fptr)d_in[13], bv1 = (fptr)d_in[14], gv1 = (fptr)d_in[15], Bv1 = (fptr)d_in[16];
    fptr Wv2 = (fptr)d_in[17], bv2 = (fptr)d_in[18], gv2 = (fptr)d_in[19], Bv2 = (fptr)d_in[20];
    fptr Wb = (fptr)d_in[21], bb = (fptr)d_in[22];
    fptr Wl1 = (fptr)d_in[23], bl1 = (fptr)d_in[24];
    fptr Wl2 = (fptr)d_in[25], bl2 = (fptr)d_in[26];

    const size_t MB = 1024 * 1024;
    char* w = (char*)d_ws;
    unsigned short* AbfK  = (unsigned short*)w;                      // 0..64 MB
    unsigned short* AbfV2 = (unsigned short*)(w + 64 * MB);          // 64..128 MB
    __hip_bfloat16* zV2   = (__hip_bfloat16*)(w + 128 * MB);         // 128..192 MB
    unsigned short* WtK   = (unsigned short*)(w + 192 * MB);         // 2 MB
    unsigned short* WtV2  = (unsigned short*)(w + 194 * MB);         // 2 MB
    unsigned short* Wbt   = (unsigned short*)(w + 196 * MB);         // 16 KB
    unsigned short* qwbuf = (unsigned short*)(w + 196 * MB + 65536); // 2 MB
    float* qws      = (float*)(w + 196 * MB + 65536 + 2 * MB);       // 64 KB
    float* v1ws     = qws + 16 * 1024;                               // 64 KB
    float* logits   = v1ws + 16 * 1024;                              // 1 MB
    float* poolpart = logits + 16 * 8 * 2048;                        // 512 KB (-> <200 MB total)
    float* out = (float*)d_out;

    hipLaunchKernelGGL(prep, dim3(33537), dim3(256), 0, stream,
                       key, value2, AbfK, AbfV2,
                       Wk, Wv2, WtK, WtV2, Wb, Wbt,
                       query, Wq, bq, gq, Bq, value1, Wv1, bv1, gv1, Bv1,
                       qws, v1ws);
    hipLaunchKernelGGL(qwb_prep, dim3(128), dim3(256), 0, stream,
                       (bfp)Wbt, qws, qwbuf);
    hipLaunchKernelGGL(gemm_fused, dim3(512, 8), dim3(256), 0, stream,
                       (bfp)AbfK, (bfp)WtK, bk, gk, Bk,
                       (bfp)AbfV2, (bfp)WtV2, bv2, gv2, Bv2,
                       (bfp)qwbuf, maskp, bb, Wl1, bl1, logits, poolpart, zV2);
    hipLaunchKernelGGL(finalize_fused, dim3(8, 16), dim3(512), 0, stream,
                       logits, poolpart, maskp, zV2, v1ws, Wl2, bl2, out);
}